// Round 6
// baseline (939.058 us; speedup 1.0000x reference)
//
#include <hip/hip_runtime.h>
#include <hip/hip_bf16.h>

// Problem constants (B=1)
#define S_LEN   2048
#define NH      16
#define ROPE_D  64
#define IDIM    128
#define KV_LORA 512
#define CDIM    576            // KV_LORA + ROPE_D (compressed attention dim)
#define TOPK_K  1024
#define SCALING 0.08838834764831845f   // 128^-0.5

typedef __attribute__((ext_vector_type(4))) float f32x4;
typedef __attribute__((ext_vector_type(8))) short s16x8;
typedef __attribute__((ext_vector_type(4))) int   i32x4;
typedef __attribute__((ext_vector_type(8))) unsigned short u16x8;

static __device__ __forceinline__ unsigned short bf16_bits(float v)
{
    __hip_bfloat16 h = __float2bfloat16(v);
    return *(unsigned short*)&h;
}

#define BM 64
#define BN 64
#define BK 16

// ---------------------------------------------------------------------------
// Fused split-K projection: part[ks][m][n] = hidden[m, ks*256:+256] @ W^T
// ---------------------------------------------------------------------------
#define PKC 256

__global__ __launch_bounds__(256)
void proj_splitk(const float* __restrict__ hidden, const float* __restrict__ wk_w,
                 const float* __restrict__ wproj_w, float* __restrict__ part)
{
    int nt = blockIdx.x, mt = blockIdx.y, ks = blockIdx.z;
    int n0 = nt * 64, m0 = mt * 64, k00 = ks * PKC;
    __shared__ float As[BK][BM + 1];
    __shared__ float Bs[BK][BN + 1];
    int tid = threadIdx.x, tx = tid & 15, ty = tid >> 4;
    float acc[4][4] = {};
    for (int k0 = 0; k0 < PKC; k0 += BK) {
        for (int t = tid; t < BM * BK; t += 256) {
            int m = t >> 4, kk = t & 15;
            As[kk][m] = hidden[(long)(m0 + m) * 2048 + k00 + k0 + kk];
        }
        for (int t = tid; t < BN * BK; t += 256) {
            int nn = t >> 4, kk = t & 15;
            int n = n0 + nn;
            float v = 0.f;
            if (n < 128)      v = wk_w[(long)n * 2048 + k00 + k0 + kk];
            else if (n < 144) v = wproj_w[(long)(n - 128) * 2048 + k00 + k0 + kk];
            Bs[kk][nn] = v;
        }
        __syncthreads();
        #pragma unroll
        for (int kk = 0; kk < BK; kk++) {
            float a[4], b[4];
            #pragma unroll
            for (int i = 0; i < 4; i++) a[i] = As[kk][ty * 4 + i];
            #pragma unroll
            for (int j = 0; j < 4; j++) b[j] = Bs[kk][tx * 4 + j];
            #pragma unroll
            for (int i = 0; i < 4; i++)
                #pragma unroll
                for (int j = 0; j < 4; j++) acc[i][j] += a[i] * b[j];
        }
        __syncthreads();
    }
    for (int i = 0; i < 4; i++) {
        int m = m0 + ty * 4 + i;
        for (int j = 0; j < 4; j++) {
            int n = n0 + tx * 4 + j;
            if (n < 144) part[((long)ks * S_LEN + m) * 144 + n] = acc[i][j];
        }
    }
}

__global__ void proj_reduce(const float* __restrict__ part, float* __restrict__ ckv,
                            float* __restrict__ wmat)
{
    int i = blockIdx.x * 256 + threadIdx.x;
    if (i >= S_LEN * 144) return;
    int m = i / 144, n = i % 144;
    float s = 0.f;
    #pragma unroll
    for (int ks = 0; ks < 8; ks++) s += part[((long)ks * S_LEN + m) * 144 + n];
    if (n < 128) ckv[(long)m * 128 + n] = s;
    else         wmat[(long)m * 16 + (n - 128)] = s;
}

// ---------------------------------------------------------------------------
// Elementwise packs
// ---------------------------------------------------------------------------
__global__ void pack_split(const float* __restrict__ x, unsigned short* __restrict__ hi,
                           unsigned short* __restrict__ lo, long n)
{
    long i = (long)blockIdx.x * 256 + threadIdx.x;
    if (i < n) {
        float v = x[i];
        __hip_bfloat16 h = __float2bfloat16(v);
        float hv = __bfloat162float(h);
        hi[i] = *(unsigned short*)&h;
        lo[i] = bf16_bits(v - hv);
    }
}

__global__ void pack_bf16(const float* __restrict__ x, unsigned short* __restrict__ y, long n)
{
    long i = (long)blockIdx.x * 256 + threadIdx.x;
    if (i < n) y[i] = bf16_bits(x[i]);
}

// kbT[h][n(512)][k(128)] = kv_b[(h*256 + k)*512 + n]
__global__ void pack_kbT(const float* __restrict__ kv_b, unsigned short* __restrict__ kbT)
{
    long i = (long)blockIdx.x * 256 + threadIdx.x;
    int k = i & 127, n = (i >> 7) & 511, h = i >> 16;
    kbT[i] = bf16_bits(kv_b[((long)h * 256 + k) * 512 + n]);
}

// vb[h][d(128)][r(512)] = kv_b[(h*256+128+d)*512 + r]
__global__ void pack_vb(const float* __restrict__ kv_b, unsigned short* __restrict__ vb)
{
    long i = (long)blockIdx.x * 256 + threadIdx.x;
    int r = i & 511, d = (i >> 9) & 127, h = i >> 16;
    vb[i] = bf16_bits(kv_b[((long)h * 256 + 128 + d) * 512 + r]);
}

// ---------------------------------------------------------------------------
// w = |gemm_out + bias|, in-place
// ---------------------------------------------------------------------------
__global__ void absbias_inplace(float* __restrict__ w, const float* __restrict__ b)
{
    int idx = blockIdx.x * 256 + threadIdx.x;
    if (idx < S_LEN * NH) w[idx] = fabsf(w[idx] + b[idx & 15]);
}

// ---------------------------------------------------------------------------
// In-place interleaved RoPE on ql -> index_q
// ---------------------------------------------------------------------------
__global__ void rope_iq_inplace(float* __restrict__ ql,
                                const float* __restrict__ cosb,
                                const float* __restrict__ sinb)
{
    int s = blockIdx.x, h = blockIdx.y, i = threadIdx.x;   // i in [0,64)
    float* row = ql + (long)s * (NH * IDIM) + h * IDIM;
    float y  = (i < 32) ? row[2 * i]     : row[2 * (i - 32) + 1];
    float yr = (i < 32) ? -row[2 * i + 1] : row[2 * (i - 32)];
    float c  = cosb[s * ROPE_D + i];
    float sn = sinb[s * ROPE_D + i];
    float val = y * c + yr * sn;
    __syncthreads();
    row[i] = val;
}

// ---------------------------------------------------------------------------
// In-place build of index_k from ckv rows
// ---------------------------------------------------------------------------
__global__ void build_ik_inplace(float* __restrict__ ckv,
                                 const float* __restrict__ cosb,
                                 const float* __restrict__ sinb,
                                 const float* __restrict__ knw)
{
    int k = blockIdx.x, i = threadIdx.x;   // i in [0,64)
    float* row = ckv + (long)k * IDIM;
    float y  = (i < 32) ? row[2 * i]     : row[2 * (i - 32) + 1];
    float yr = (i < 32) ? -row[2 * i + 1] : row[2 * (i - 32)];
    float c  = cosb[k * ROPE_D + i];
    float sn = sinb[k * ROPE_D + i];
    float rot = y * c + yr * sn;
    float xp = row[ROPE_D + i];
    float ss = xp * xp;
    for (int off = 32; off; off >>= 1) ss += __shfl_down(ss, off, 64);
    ss = __shfl(ss, 0, 64);
    float nv = xp * rsqrtf(ss / 64.f + 1e-6f) * knw[i];
    __syncthreads();
    row[i] = rot;
    row[ROPE_D + i] = nv;
}

// ---------------------------------------------------------------------------
// Split-bf16 MFMA GEMM: C(fp32) = A @ B^T, A,B given as (hi,lo) bf16 pairs.
// ---------------------------------------------------------------------------
__global__ __launch_bounds__(256)
void gemm_split3(const unsigned short* __restrict__ Ah, const unsigned short* __restrict__ Al,
                 const unsigned short* __restrict__ Bh, const unsigned short* __restrict__ Bl,
                 float* __restrict__ C, int N, int K, int lda, int ldb, int ldc)
{
    int tid = threadIdx.x, wv = tid >> 6, ln = tid & 63, g = ln >> 4, lo = ln & 15;
    int m0 = blockIdx.y * 64 + wv * 16, n0 = blockIdx.x * 64;
    f32x4 acc[4] = {};
    for (int kc = 0; kc < K; kc += 32) {
        long aoff = (long)(m0 + lo) * lda + kc + g * 8;
        s16x8 ah = *(const s16x8*)&Ah[aoff];
        s16x8 al = *(const s16x8*)&Al[aoff];
        #pragma unroll
        for (int nt = 0; nt < 4; nt++) {
            long boff = (long)(n0 + nt * 16 + lo) * ldb + kc + g * 8;
            s16x8 bh = *(const s16x8*)&Bh[boff];
            s16x8 bl = *(const s16x8*)&Bl[boff];
            acc[nt] = __builtin_amdgcn_mfma_f32_16x16x32_bf16(ah, bh, acc[nt], 0, 0, 0);
            acc[nt] = __builtin_amdgcn_mfma_f32_16x16x32_bf16(ah, bl, acc[nt], 0, 0, 0);
            acc[nt] = __builtin_amdgcn_mfma_f32_16x16x32_bf16(al, bh, acc[nt], 0, 0, 0);
        }
    }
    #pragma unroll
    for (int nt = 0; nt < 4; nt++)
        #pragma unroll
        for (int r = 0; r < 4; r++)
            C[(long)(m0 + g * 4 + r) * ldc + n0 + nt * 16 + lo] = acc[nt][r];
}

// ---------------------------------------------------------------------------
// Plain bf16 MFMA GEMM: C = A @ B^T. K explicit (lda may exceed K).
// ---------------------------------------------------------------------------
template<typename TC>
__global__ __launch_bounds__(256)
void gemm_bf16(const unsigned short* __restrict__ A, const unsigned short* __restrict__ B,
               TC* __restrict__ C, int K, int lda, int ldb, int ldc,
               long sA, long sB, long sC)
{
    A += (long)blockIdx.z * sA; B += (long)blockIdx.z * sB; C += (long)blockIdx.z * sC;
    int tid = threadIdx.x, wv = tid >> 6, ln = tid & 63, g = ln >> 4, lo = ln & 15;
    int m0 = blockIdx.y * 64 + wv * 16, n0 = blockIdx.x * 64;
    f32x4 acc[4] = {};
    for (int kc = 0; kc < K; kc += 32) {
        s16x8 a = *(const s16x8*)&A[(long)(m0 + lo) * lda + kc + g * 8];
        #pragma unroll
        for (int nt = 0; nt < 4; nt++) {
            s16x8 b = *(const s16x8*)&B[(long)(n0 + nt * 16 + lo) * ldb + kc + g * 8];
            acc[nt] = __builtin_amdgcn_mfma_f32_16x16x32_bf16(a, b, acc[nt], 0, 0, 0);
        }
    }
    #pragma unroll
    for (int nt = 0; nt < 4; nt++)
        #pragma unroll
        for (int r = 0; r < 4; r++)
            C[(long)(m0 + g * 4 + r) * ldc + n0 + nt * 16 + lo] = (TC)acc[nt][r];
}

// ---------------------------------------------------------------------------
// Indexer scores via split-bf16 MFMA.
// ---------------------------------------------------------------------------
__global__ __launch_bounds__(256)
void scores_mfma(const unsigned short* __restrict__ iq_hi, const unsigned short* __restrict__ iq_lo,
                 const unsigned short* __restrict__ ik_hi, const unsigned short* __restrict__ ik_lo,
                 const float* __restrict__ w, float* __restrict__ sc)
{
    int bk = blockIdx.x, bq = blockIdx.y;
    if (bk > bq) return;
    int q0 = bq * 64, k0 = bk * 64;
    __shared__ __align__(16) unsigned short Khi[64][136];
    __shared__ __align__(16) unsigned short Klo[64][136];
    __shared__ float Ws[64][17];
    int tid = threadIdx.x, wv = tid >> 6, ln = tid & 63, g = ln >> 4, lo = ln & 15;

    for (int i = tid; i < 64 * 16; i += 256) {
        int r = i >> 4, c8 = i & 15;
        *(u16x8*)&Khi[r][c8 * 8] = *(const u16x8*)&ik_hi[(long)(k0 + r) * IDIM + c8 * 8];
        *(u16x8*)&Klo[r][c8 * 8] = *(const u16x8*)&ik_lo[(long)(k0 + r) * IDIM + c8 * 8];
    }
    for (int i = tid; i < 64 * 16; i += 256)
        Ws[i >> 4][i & 15] = w[(long)(q0 + (i >> 4)) * NH + (i & 15)];
    __syncthreads();

    float fin[4][4][4] = {};   // [mt][nt][r]
    #pragma unroll
    for (int hh = 0; hh < 4; hh++) {
        int h = wv * 4 + hh;
        #pragma unroll
        for (int mg = 0; mg < 2; mg++) {
            f32x4 acc[2][4] = {};
            #pragma unroll
            for (int kc = 0; kc < 4; kc++) {
                s16x8 ah[2], al[2];
                #pragma unroll
                for (int mi = 0; mi < 2; mi++) {
                    long off = ((long)(q0 + (mg * 2 + mi) * 16 + lo) * NH + h) * IDIM + kc * 32 + g * 8;
                    ah[mi] = *(const s16x8*)&iq_hi[off];
                    al[mi] = *(const s16x8*)&iq_lo[off];
                }
                #pragma unroll
                for (int nt = 0; nt < 4; nt++) {
                    s16x8 bh = *(const s16x8*)&Khi[nt * 16 + lo][kc * 32 + g * 8];
                    s16x8 bl = *(const s16x8*)&Klo[nt * 16 + lo][kc * 32 + g * 8];
                    #pragma unroll
                    for (int mi = 0; mi < 2; mi++) {
                        acc[mi][nt] = __builtin_amdgcn_mfma_f32_16x16x32_bf16(ah[mi], bh, acc[mi][nt], 0, 0, 0);
                        acc[mi][nt] = __builtin_amdgcn_mfma_f32_16x16x32_bf16(ah[mi], bl, acc[mi][nt], 0, 0, 0);
                        acc[mi][nt] = __builtin_amdgcn_mfma_f32_16x16x32_bf16(al[mi], bh, acc[mi][nt], 0, 0, 0);
                    }
                }
            }
            #pragma unroll
            for (int mi = 0; mi < 2; mi++) {
                int mt = mg * 2 + mi;
                #pragma unroll
                for (int r = 0; r < 4; r++) {
                    float wqh = Ws[mt * 16 + g * 4 + r][h];
                    #pragma unroll
                    for (int nt = 0; nt < 4; nt++) {
                        float v = acc[mi][nt][r] * SCALING;
                        v = v > 0.f ? v : 0.f;
                        fin[mt][nt][r] += v * wqh;
                    }
                }
            }
        }
    }
    __syncthreads();
    float (*FinBuf)[68] = (float(*)[68])&Khi[0][0];
    for (int wt = 0; wt < 4; wt++) {
        if (wv == wt) {
            #pragma unroll
            for (int mt = 0; mt < 4; mt++)
                #pragma unroll
                for (int r = 0; r < 4; r++)
                    #pragma unroll
                    for (int nt = 0; nt < 4; nt++) {
                        if (wt == 0) FinBuf[mt * 16 + g * 4 + r][nt * 16 + lo] = fin[mt][nt][r];
                        else         FinBuf[mt * 16 + g * 4 + r][nt * 16 + lo] += fin[mt][nt][r];
                    }
        }
        __syncthreads();
    }
    for (int i = tid; i < 64 * 16; i += 256) {
        int r = i >> 4, c4 = i & 15;
        *(f32x4*)&sc[(long)(q0 + r) * S_LEN + k0 + c4 * 4] = *(f32x4*)&FinBuf[r][c4 * 4];
    }
}

// ---------------------------------------------------------------------------
// Exact top-1024 per row via radix-select on float bits (scores >= 0).
// ---------------------------------------------------------------------------
__device__ __forceinline__ int block_scan_excl(int v, volatile int* lds, int tid, int* total)
{
    lds[tid] = v;
    __syncthreads();
    int x = v;
    for (int off = 1; off < 256; off <<= 1) {
        int y = (tid >= off) ? lds[tid - off] : 0;
        __syncthreads();
        x += y;
        lds[tid] = x;
        __syncthreads();
    }
    int t = lds[255];
    __syncthreads();
    *total = t;
    return x - v;
}

__global__ __launch_bounds__(256)
void topk_kernel(const float* __restrict__ sc, int* __restrict__ sel_idx)
{
    __shared__ int lds[256];
    __shared__ int wsum[4];
    int q = blockIdx.x, tid = threadIdx.x;
    int n = q + 1;
    int* row_sel = sel_idx + (long)q * TOPK_K;
    if (n <= TOPK_K) {
        for (int i = tid; i < n; i += 256) row_sel[i] = i;
        return;
    }
    const float* row = sc + (long)q * S_LEN;
    unsigned bits[8];
    int base = tid * 8;
    #pragma unroll
    for (int i = 0; i < 8; i++) {
        int k = base + i;
        bits[i] = (k < n) ? __float_as_uint(row[k]) : 0u;
    }
    unsigned prefix = 0;
    for (int bit = 30; bit >= 0; bit--) {
        unsigned cand = prefix | (1u << bit);
        int c = 0;
        #pragma unroll
        for (int i = 0; i < 8; i++) c += (bits[i] >= cand) ? 1 : 0;
        for (int off = 32; off; off >>= 1) c += __shfl_down(c, off, 64);
        if ((tid & 63) == 0) wsum[tid >> 6] = c;
        __syncthreads();
        int total = wsum[0] + wsum[1] + wsum[2] + wsum[3];
        __syncthreads();
        if (total >= TOPK_K) prefix = cand;
    }
    unsigned v = prefix;
    int lgt = 0, leq = 0;
    #pragma unroll
    for (int i = 0; i < 8; i++) {
        int k = base + i;
        if (k >= n) break;
        if (bits[i] > v) lgt++;
        else if (bits[i] == v) leq++;
    }
    int tot_gt, tot_eq;
    int gt_off = block_scan_excl(lgt, lds, tid, &tot_gt);
    int eq_off = block_scan_excl(leq, lds, tid, &tot_eq);
    int fill = TOPK_K - tot_gt;
    int gpos = gt_off, epos = eq_off;
    for (int i = 0; i < 8; i++) {
        int k = base + i;
        if (k >= n) break;
        if (bits[i] > v) {
            row_sel[gpos++] = k;
        } else if (bits[i] == v) {
            if (epos < fill) row_sel[tot_gt + epos] = k;
            epos++;
        }
    }
}

// ---------------------------------------------------------------------------
// bf16 packs for the attention path
// ---------------------------------------------------------------------------
__global__ void pack_kv(const float* __restrict__ k_pass, const float* __restrict__ k_rot,
                        __hip_bfloat16* __restrict__ kvb)
{
    int k = blockIdx.x;
    for (int i = threadIdx.x; i < CDIM; i += 256) {
        float v = (i < KV_LORA) ? k_pass[(long)k * KV_LORA + i]
                                : k_rot[(long)k * ROPE_D + (i - KV_LORA)];
        kvb[(long)k * CDIM + i] = __float2bfloat16(v);
    }
}

__global__ void pack_qrot(const float* __restrict__ q_rot, __hip_bfloat16* __restrict__ Qcat)
{
    int q = blockIdx.x;
    for (int j = threadIdx.x; j < NH * ROPE_D; j += 256) {
        int h = j >> 6, i = j & 63;
        Qcat[((long)q * NH + h) * CDIM + KV_LORA + i] =
            __float2bfloat16(q_rot[((long)h * S_LEN + q) * ROPE_D + i]);
    }
}

// ---------------------------------------------------------------------------
// MLA sparse attention v8: v7 structure + KT sidecar for conflict-free PV.
// Changes vs v7 (verified base, 304us):
//  - staging units reassigned: wave wv gathers its OWN PV dims wv*128..+128
//    (8 units) + 1/4 of rope (cu = 16+(wv>>1), khu = wv&1). Row-write formula
//    and S phase are byte-identical to v7.
//  - KT sidecar (per-wave private, 16 chunks x 132 words, v5's layout):
//    word(cl, d, i) = cl*132 + d*16 + i holds keys (2i, 2i+1) @ dim
//    wv*128 + cl*8 + d. Built from the gathered Vst registers via one
//    __shfl_xor(.,4) pair-exchange + bit-packs, 4 ds_write_b32/unit (2-way
//    banks). PV B-frags become v5's VERIFIED b128 read
//    KT[cl*132 + d*16 + g*4] -> deletes the 64 4-way-conflicted u16 reads.
//  - Row buffer single-buffered (S reads complete before sync1; writes for
//    t+1 happen after PV). LDS = 36,864 + 34,816 + 4,096 = 75,776
//    -> still 2 blocks/CU. 2 syncthreads/tile, compiler-managed waitcnts.
// ---------------------------------------------------------------------------
__global__ __launch_bounds__(256, 2)
void attn_mla8(const __hip_bfloat16* __restrict__ Qcat,
               const __hip_bfloat16* __restrict__ kvb,
               const int* __restrict__ sel_idx,
               unsigned short* __restrict__ Oout)   // == (unsigned short*)Qcat
{
    __shared__ __align__(16) unsigned int Row[9216];     // 36,864 B (single buf)
    __shared__ __align__(16) unsigned int KT[4][2176];   // 34,816 B (per-wave)
    __shared__ __align__(16) float Sp[4][64][4];         //  4,096 B partial-S

    const int q   = blockIdx.x;
    const int tid = threadIdx.x;
    const int wv  = tid >> 6;            // wave 0..3
    const int ln  = tid & 63;
    const int g   = ln >> 4, lo = ln & 15;
    const int kh  = wv >> 1, dh = wv & 1;   // S-split: key-half, dim-half
    const int k_l = ln >> 2, oct = ln & 3;  // staging roles
    const int par = k_l & 1;                // key parity within pair
    const int cnt = (q + 1 < TOPK_K) ? (q + 1) : TOPK_K;
    const int* sel = sel_idx + (long)q * TOPK_K;
    const unsigned short* kvu = (const unsigned short*)kvb;
    const unsigned short* qrow = (const unsigned short*)Qcat + (long)q * NH * CDIM;

    // Q frags for this wave's 9 S-chunks (dims dh*288 + cc*32 + g*8)
    s16x8 Qf[9];
    #pragma unroll
    for (int cc = 0; cc < 9; cc++)
        Qf[cc] = *(const s16x8*)&qrow[lo * CDIM + (dh * 9 + cc) * 32 + g * 8];

    float m_run = -1e30f, l_run = 0.f;
    f32x4 O[8];
    #pragma unroll
    for (int s = 0; s < 8; s++) O[s] = (f32x4){0.f, 0.f, 0.f, 0.f};

    const int ntl = (cnt + 31) >> 5;
    unsigned int* KTw = &KT[wv][0];

    // staging unit uu -> (cu, khu): uu<8: cu = wv*4 + (uu>>1), khu = uu&1
    //                    uu=8 (rope): cu = 16 + (wv>>1), khu = wv&1
    // lane gathers key khu*16+k_l, dims cu*32 + oct*8 .. +8 (16B)

    // ---- prologue: gather + commit tile 0 ----
    i32x4 Vst[9];
    int i0 = ln & 31;
    int selvA = sel[i0 < cnt ? i0 : cnt - 1];
    #pragma unroll
    for (int uu = 0; uu < 9; uu++) {
        int cu  = (uu < 8) ? (wv * 4 + (uu >> 1)) : (16 + (wv >> 1));
        int khu = (uu < 8) ? (uu & 1) : (wv & 1);
        int row = __shfl(selvA, khu * 16 + k_l, 64);
        Vst[uu] = *(const i32x4*)(kvu + (long)row * CDIM + cu * 32 + oct * 8);
    }
    {
        char* Kn = (char*)&Row[0];
        #pragma unroll
        for (int uu = 0; uu < 9; uu++) {
            int cu  = (uu < 8) ? (wv * 4 + (uu >> 1)) : (16 + (wv >> 1));
            int khu = (uu < 8) ? (uu & 1) : (wv & 1);
            int byte = (cu * 2 + (oct >> 1)) * 1024 + (khu * 16 + k_l) * 32 + (oct & 1) * 16;
            *(i32x4*)(Kn + byte) = Vst[uu];
        }
        #pragma unroll
        for (int uu = 0; uu < 8; uu++) {
            unsigned w0 = (unsigned)Vst[uu][0], w1 = (unsigned)Vst[uu][1];
            unsigned w2 = (unsigned)Vst[uu][2], w3 = (unsigned)Vst[uu][3];
            unsigned r0 = __shfl_xor(par ? w0 : w2, 4, 64);
            unsigned r1 = __shfl_xor(par ? w1 : w3, 4, 64);
            unsigned u0 = par ? r0 : w0, u1 = par ? r1 : w1;
            unsigned v0 = par ? w2 : r0, v1 = par ? w3 : r1;
            int cl = (uu >> 1) * 4 + oct;
            int ii = (uu & 1) * 8 + (k_l >> 1);
            int base = cl * 132 + par * 64 + ii;
            KTw[base]      = (u0 & 0xffffu) | (v0 << 16);
            KTw[base + 16] = (u0 >> 16)     | (v0 & 0xffff0000u);
            KTw[base + 32] = (u1 & 0xffffu) | (v1 << 16);
            KTw[base + 48] = (u1 >> 16)     | (v1 & 0xffff0000u);
        }
    }
    int i1 = 32 + (ln & 31);
    int selvN = sel[i1 < cnt ? i1 : cnt - 1];
    __syncthreads();

    // S-read lane base: byte(key=kh*16+lo, D=c*32+g*8)
    //   = ((c*4+g)>>1)*1024 + (kh*16+lo)*32 + (g&1)*16
    const int sread_key = (kh * 16 + lo) * 32 + ((g & 1) << 4);
    const int idxA = (g & 1) * 32 + lo;   // pa-shuffle source lanes
    const int idxB = idxA + 16;

    for (int t = 0; t < ntl; t++) {
        const int kb = t * 32;
        const bool hasn = (t + 1 < ntl);

        // --- issue next tile's gathers (fly over this tile's compute)
        if (hasn) {
            #pragma unroll
            for (int uu = 0; uu < 9; uu++) {
                int cu  = (uu < 8) ? (wv * 4 + (uu >> 1)) : (16 + (wv >> 1));
                int khu = (uu < 8) ? (uu & 1) : (wv & 1);
                int row = __shfl(selvN, khu * 16 + k_l, 64);
                Vst[uu] = *(const i32x4*)(kvu + (long)row * CDIM + cu * 32 + oct * 8);
            }
        }
        int ni = kb + 64 + (ln & 31);
        int selvNN = sel[ni < cnt ? ni : cnt - 1];

        // --- S partial: 9 chunks (this wave's dims), keys kh*16..+16
        const char* Kc = (const char*)&Row[0];
        f32x4 Sacc = (f32x4){0.f, 0.f, 0.f, 0.f};
        #pragma unroll
        for (int cc = 0; cc < 9; cc++) {
            int c = dh * 9 + cc;
            s16x8 av = *(const s16x8*)(Kc + ((c * 4 + g) >> 1) * 1024 + sread_key);
            Sacc = __builtin_amdgcn_mfma_f32_16x16x32_bf16(av, Qf[cc], Sacc, 0, 0, 0);
        }
        *(f32x4*)&Sp[wv][ln][0] = Sacc;
        __syncthreads();   // sync1: partials ready; all row reads done

        f32x4 S0 = *(const f32x4*)&Sp[0][ln][0];
        { f32x4 tmp = *(const f32x4*)&Sp[1][ln][0]; S0 += tmp; }
        f32x4 S1 = *(const f32x4*)&Sp[2][ln][0];
        { f32x4 tmp = *(const f32x4*)&Sp[3][ln][0]; S1 += tmp; }

        // --- online softmax over 32 keys (head = lo, replicated across quads)
        float pv[8];
        float mx = -1e30f;
        #pragma unroll
        for (int r = 0; r < 4; r++) {
            float s = S0[r] * SCALING;
            if (kb + g * 4 + r >= cnt) s = -1e30f;
            pv[r] = s;
            mx = fmaxf(mx, s);
        }
        #pragma unroll
        for (int r = 0; r < 4; r++) {
            float s = S1[r] * SCALING;
            if (kb + 16 + g * 4 + r >= cnt) s = -1e30f;
            pv[4 + r] = s;
            mx = fmaxf(mx, s);
        }
        mx = fmaxf(mx, __shfl_xor(mx, 16, 64));
        mx = fmaxf(mx, __shfl_xor(mx, 32, 64));
        float mn = fmaxf(m_run, mx);
        float al = __expf(m_run - mn);
        float sum = 0.f;
        #pragma unroll
        for (int j = 0; j < 8; j++) { float e = __expf(pv[j] - mn); pv[j] = e; sum += e; }
        sum += __shfl_xor(sum, 16, 64);
        sum += __shfl_xor(sum, 32, 64);
        m_run = mn;
        l_run = l_run * al + sum;

        // --- pa frag in-register: W[a][c] = pack(pv[a*4+2c], pv[a*4+2c+1])
        int W00 = (int)((unsigned)bf16_bits(pv[0]) | ((unsigned)bf16_bits(pv[1]) << 16));
        int W01 = (int)((unsigned)bf16_bits(pv[2]) | ((unsigned)bf16_bits(pv[3]) << 16));
        int W10 = (int)((unsigned)bf16_bits(pv[4]) | ((unsigned)bf16_bits(pv[5]) << 16));
        int W11 = (int)((unsigned)bf16_bits(pv[6]) | ((unsigned)bf16_bits(pv[7]) << 16));
        int A0 = __shfl(W00, idxA, 64), A1 = __shfl(W01, idxA, 64);
        int A2 = __shfl(W00, idxB, 64), A3 = __shfl(W01, idxB, 64);
        int B0 = __shfl(W10, idxA, 64), B1 = __shfl(W11, idxA, 64);
        int B2 = __shfl(W10, idxB, 64), B3 = __shfl(W11, idxB, 64);
        i32x4 paw;
        paw[0] = (g < 2) ? A0 : B0;
        paw[1] = (g < 2) ? A1 : B1;
        paw[2] = (g < 2) ? A2 : B2;
        paw[3] = (g < 2) ? A3 : B3;
        s16x8 pa = __builtin_bit_cast(s16x8, paw);

        // --- rescale O by per-head alpha (head = g*4+r)
        float alh[4];
        #pragma unroll
        for (int r = 0; r < 4; r++) alh[r] = __shfl(al, g * 4 + r, 64);
        #pragma unroll
        for (int s = 0; s < 8; s++) {
            O[s][0] *= alh[0]; O[s][1] *= alh[1]; O[s][2] *= alh[2]; O[s][3] *= alh[3];
        }

        // --- PV: this wave's 128 output dims via v5-verified KT b128 frags
        // dim D = wv*128 + s*16 + lo; keys g*8+j = KT words cl*132+d*16+g*4..+4
        #pragma unroll
        for (int s = 0; s < 8; s++) {
            int cl = s * 2 + (lo >> 3);
            s16x8 bv = *(const s16x8*)&KTw[cl * 132 + (lo & 7) * 16 + g * 4];
            O[s] = __builtin_amdgcn_mfma_f32_16x16x32_bf16(pa, bv, O[s], 0, 0, 0);
        }

        // --- commit next tile: row copy + KT sidecar (from Vst registers;
        //     compiler inserts the vmcnt wait). Row writes are safe: all
        //     S reads of tile t finished before sync1; KT is wave-private.
        if (hasn) {
            char* Kn = (char*)&Row[0];
            #pragma unroll
            for (int uu = 0; uu < 9; uu++) {
                int cu  = (uu < 8) ? (wv * 4 + (uu >> 1)) : (16 + (wv >> 1));
                int khu = (uu < 8) ? (uu & 1) : (wv & 1);
                int byte = (cu * 2 + (oct >> 1)) * 1024 + (khu * 16 + k_l) * 32 + (oct & 1) * 16;
                *(i32x4*)(Kn + byte) = Vst[uu];
            }
            #pragma unroll
            for (int uu = 0; uu < 8; uu++) {
                unsigned w0 = (unsigned)Vst[uu][0], w1 = (unsigned)Vst[uu][1];
                unsigned w2 = (unsigned)Vst[uu][2], w3 = (unsigned)Vst[uu][3];
                unsigned r0 = __shfl_xor(par ? w0 : w2, 4, 64);
                unsigned r1 = __shfl_xor(par ? w1 : w3, 4, 64);
                unsigned u0 = par ? r0 : w0, u1 = par ? r1 : w1;
                unsigned v0 = par ? w2 : r0, v1 = par ? w3 : r1;
                int cl = (uu >> 1) * 4 + oct;
                int ii = (uu & 1) * 8 + (k_l >> 1);
                int base = cl * 132 + par * 64 + ii;
                KTw[base]      = (u0 & 0xffffu) | (v0 << 16);
                KTw[base + 16] = (u0 >> 16)     | (v0 & 0xffff0000u);
                KTw[base + 32] = (u1 & 0xffffu) | (v1 << 16);
                KTw[base + 48] = (u1 >> 16)     | (v1 & 0xffff0000u);
            }
        }
        __syncthreads();   // sync2: tile t+1 committed; Sp consumed
        selvN = selvNN;
    }

    // --- epilogue: O / l -> bf16, wave's own 128-dim slice of the Qcat row
    float linv[4];
    #pragma unroll
    for (int r = 0; r < 4; r++) linv[r] = 1.f / __shfl(l_run, g * 4 + r, 64);
    unsigned short* orow = Oout + (long)q * NH * CDIM;
    #pragma unroll
    for (int s = 0; s < 8; s++)
        #pragma unroll
        for (int r = 0; r < 4; r++)
            orow[(g * 4 + r) * KV_LORA + wv * 128 + s * 16 + lo] = bf16_bits(O[s][r] * linv[r]);
}

// ---------------------------------------------------------------------------
// Launch
// ---------------------------------------------------------------------------
extern "C" void kernel_launch(void* const* d_in, const int* in_sizes, int n_in,
                              void* d_out, int out_size, void* d_ws, size_t ws_size,
                              hipStream_t stream)
{
    const float* q_latent = (const float*)d_in[0];   // (2048,1536)
    const float* hidden   = (const float*)d_in[1];   // (2048,2048)
    const float* cosp     = (const float*)d_in[2];   // (2048,64)
    const float* sinp     = (const float*)d_in[3];   // (2048,64)
    const float* q_pass   = (const float*)d_in[4];   // (16,2048,128)
    const float* q_rot    = (const float*)d_in[5];   // (16,2048,64)
    const float* k_pass   = (const float*)d_in[6];   // (2048,512)
    const float* k_rot    = (const float*)d_in[7];   // (2048,64)
    const float* kv_b     = (const float*)d_in[9];   // (4096,512)
    const float* wq_b_w   = (const float*)d_in[10];  // (2048,1536)
    const float* wk_w     = (const float*)d_in[11];  // (128,2048)
    const float* k_norm_w = (const float*)d_in[12];  // (64)
    const float* wproj_w  = (const float*)d_in[13];  // (16,2048)
    const float* wproj_b  = (const float*)d_in[14];  // (16)

    float* ws = (float*)d_ws;
    // Persistent: sel_idx
    int* sel_idx = (int*)ws;                                       // [0 .. 2,097,152)
    // Phase 1a: split inputs for ql GEMM
    unsigned short* qlat_hi = (unsigned short*)(ws + 2097152);
    unsigned short* qlat_lo = (unsigned short*)(ws + 3670016);
    unsigned short* wq_hi   = (unsigned short*)(ws + 5242880);
    unsigned short* wq_lo   = (unsigned short*)(ws + 6815744);     // ends 8,388,608 f
    float* ql = ws + 8388608;                                      // 4,194,304 f -> 12,582,912
    // Phase 1b (after ql GEMM; aliases qlat/wq region):
    unsigned short* iq_hi = (unsigned short*)(ws + 2097152);
    unsigned short* iq_lo = (unsigned short*)(ws + 4194304);
    unsigned short* ik_hi = (unsigned short*)(ws + 6291456);
    unsigned short* ik_lo = (unsigned short*)(ws + 6422528);
    float* wmat = ws + 6553600;                                    // 32,768 f
    float* ckv  = ws + 6586368;                                    // 262,144 f -> 6,848,512
    float* sc   = ws + 8388608;                                    // aliases ql (dead after pack iq)
    float* part = ws + 12582912;                                   // 2,359,296 f -> 14,942,208 (phase 1 only)
    // Phase 2 (after topk; aliases phase-1):
    __hip_bfloat16* Qcat = (__hip_bfloat16*)(ws + 2097152);        // ends f-off 11,534,336; O written in-place
    __hip_bfloat16* kvb  = (__hip_bfloat16*)(ws + 11534336);       // -> 12,124,160
    unsigned short* kbT  = (unsigned short*)(ws + 12124160);       // -> 12,648,448
    unsigned short* vb   = (unsigned short*)(ws + 12648448);       // -> 13,172,736
    unsigned short* qp   = (unsigned short*)(ws + 13172736);       // -> 15,269,888  (61.1 MB peak)

    dim3 b256(256);
    // --- indexer path (split-bf16 MFMA, selection-exact) ---
    pack_split<<<dim3(12288), b256, 0, stream>>>(q_latent, qlat_hi, qlat_lo, 2048L * 1536);
    pack_split<<<dim3(12288), b256, 0, stream>>>(wq_b_w, wq_hi, wq_lo, 2048L * 1536);
    gemm_split3<<<dim3(32, 32), b256, 0, stream>>>(qlat_hi, qlat_lo, wq_hi, wq_lo,
        ql, 2048, 1536, 1536, 1536, 2048);
    rope_iq_inplace<<<dim3(2048, 16), dim3(64), 0, stream>>>(ql, cosp, sinp);
    pack_split<<<dim3(16384), b256, 0, stream>>>(ql, iq_hi, iq_lo, 2048L * 2048);
    proj_splitk<<<dim3(3, 32, 8), b256, 0, stream>>>(hidden, wk_w, wproj_w, part);
    proj_reduce<<<dim3((S_LEN * 144 + 255) / 256), b256, 0, stream>>>(part, ckv, wmat);
    build_ik_inplace<<<dim3(2048), dim3(64), 0, stream>>>(ckv, cosp, sinp, k_norm_w);
    pack_split<<<dim3(1024), b256, 0, stream>>>(ckv, ik_hi, ik_lo, 2048L * 128);
    absbias_inplace<<<dim3(128), b256, 0, stream>>>(wmat, wproj_b);
    scores_mfma<<<dim3(32, 32), b256, 0, stream>>>(iq_hi, iq_lo, ik_hi, ik_lo, wmat, sc);
    topk_kernel<<<dim3(2048), b256, 0, stream>>>(sc, sel_idx);

    // --- attention path (bf16 MFMA, compressed space) ---
    pack_bf16<<<dim3(16384), b256, 0, stream>>>(q_pass, qp, 16L * 2048 * 128);
    pack_kbT<<<dim3(4096), b256, 0, stream>>>(kv_b, kbT);
    pack_vb<<<dim3(4096), b256, 0, stream>>>(kv_b, vb);
    pack_kv<<<dim3(2048), b256, 0, stream>>>(k_pass, k_rot, kvb);
    // q_abs[h] = qp[h] (2048x128) @ kbT[h]^T (512x128): K=128 -> Qcat[:, h, 0:512]
    gemm_bf16<__hip_bfloat16><<<dim3(8, 32, 16), b256, 0, stream>>>(
        qp, kbT, (__hip_bfloat16*)Qcat, 128, 128, 128, NH * CDIM,
        2048L * 128, 512L * 128, (long)CDIM);
    pack_qrot<<<dim3(2048), b256, 0, stream>>>(q_rot, Qcat);

    // Work-split pipelined attention with KT sidecar PV.
    attn_mla8<<<dim3(2048), dim3(256), 0, stream>>>(Qcat, kvb, sel_idx,
                                                    (unsigned short*)Qcat);
    // out[q][h][d] = O[q][h][:512] . vb[h][d][:512]; O rows live inside Qcat
    // (row stride NH*CDIM=9216, head offset h*512).
    gemm_bf16<float><<<dim3(2, 32, 16), b256, 0, stream>>>(
        (const unsigned short*)Qcat, vb, (float*)d_out,
        512, NH * CDIM, KV_LORA, NH * IDIM,
        512L, 128L * 512, (long)IDIM);
}

// Round 7
// 785.274 us; speedup vs baseline: 1.1958x; 1.1958x over previous
//
#include <hip/hip_runtime.h>
#include <hip/hip_bf16.h>

// Problem constants (B=1)
#define S_LEN   2048
#define NH      16
#define ROPE_D  64
#define IDIM    128
#define KV_LORA 512
#define CDIM    576            // KV_LORA + ROPE_D (compressed attention dim)
#define TOPK_K  1024
#define SCALING 0.08838834764831845f   // 128^-0.5

typedef __attribute__((ext_vector_type(4))) float f32x4;
typedef __attribute__((ext_vector_type(8))) short s16x8;
typedef __attribute__((ext_vector_type(4))) int   i32x4;
typedef __attribute__((ext_vector_type(8))) unsigned short u16x8;

static __device__ __forceinline__ unsigned short bf16_bits(float v)
{
    __hip_bfloat16 h = __float2bfloat16(v);
    return *(unsigned short*)&h;
}

#define BM 64
#define BN 64
#define BK 16

// ---------------------------------------------------------------------------
// Fused split-K projection: part[ks][m][n] = hidden[m, ks*256:+256] @ W^T
// ---------------------------------------------------------------------------
#define PKC 256

__global__ __launch_bounds__(256)
void proj_splitk(const float* __restrict__ hidden, const float* __restrict__ wk_w,
                 const float* __restrict__ wproj_w, float* __restrict__ part)
{
    int nt = blockIdx.x, mt = blockIdx.y, ks = blockIdx.z;
    int n0 = nt * 64, m0 = mt * 64, k00 = ks * PKC;
    __shared__ float As[BK][BM + 1];
    __shared__ float Bs[BK][BN + 1];
    int tid = threadIdx.x, tx = tid & 15, ty = tid >> 4;
    float acc[4][4] = {};
    for (int k0 = 0; k0 < PKC; k0 += BK) {
        for (int t = tid; t < BM * BK; t += 256) {
            int m = t >> 4, kk = t & 15;
            As[kk][m] = hidden[(long)(m0 + m) * 2048 + k00 + k0 + kk];
        }
        for (int t = tid; t < BN * BK; t += 256) {
            int nn = t >> 4, kk = t & 15;
            int n = n0 + nn;
            float v = 0.f;
            if (n < 128)      v = wk_w[(long)n * 2048 + k00 + k0 + kk];
            else if (n < 144) v = wproj_w[(long)(n - 128) * 2048 + k00 + k0 + kk];
            Bs[kk][nn] = v;
        }
        __syncthreads();
        #pragma unroll
        for (int kk = 0; kk < BK; kk++) {
            float a[4], b[4];
            #pragma unroll
            for (int i = 0; i < 4; i++) a[i] = As[kk][ty * 4 + i];
            #pragma unroll
            for (int j = 0; j < 4; j++) b[j] = Bs[kk][tx * 4 + j];
            #pragma unroll
            for (int i = 0; i < 4; i++)
                #pragma unroll
                for (int j = 0; j < 4; j++) acc[i][j] += a[i] * b[j];
        }
        __syncthreads();
    }
    for (int i = 0; i < 4; i++) {
        int m = m0 + ty * 4 + i;
        for (int j = 0; j < 4; j++) {
            int n = n0 + tx * 4 + j;
            if (n < 144) part[((long)ks * S_LEN + m) * 144 + n] = acc[i][j];
        }
    }
}

__global__ void proj_reduce(const float* __restrict__ part, float* __restrict__ ckv,
                            float* __restrict__ wmat)
{
    int i = blockIdx.x * 256 + threadIdx.x;
    if (i >= S_LEN * 144) return;
    int m = i / 144, n = i % 144;
    float s = 0.f;
    #pragma unroll
    for (int ks = 0; ks < 8; ks++) s += part[((long)ks * S_LEN + m) * 144 + n];
    if (n < 128) ckv[(long)m * 128 + n] = s;
    else         wmat[(long)m * 16 + (n - 128)] = s;
}

// ---------------------------------------------------------------------------
// Elementwise packs
// ---------------------------------------------------------------------------
__global__ void pack_split(const float* __restrict__ x, unsigned short* __restrict__ hi,
                           unsigned short* __restrict__ lo, long n)
{
    long i = (long)blockIdx.x * 256 + threadIdx.x;
    if (i < n) {
        float v = x[i];
        __hip_bfloat16 h = __float2bfloat16(v);
        float hv = __bfloat162float(h);
        hi[i] = *(unsigned short*)&h;
        lo[i] = bf16_bits(v - hv);
    }
}

__global__ void pack_bf16(const float* __restrict__ x, unsigned short* __restrict__ y, long n)
{
    long i = (long)blockIdx.x * 256 + threadIdx.x;
    if (i < n) y[i] = bf16_bits(x[i]);
}

// kbT[h][n(512)][k(128)] = kv_b[(h*256 + k)*512 + n]
__global__ void pack_kbT(const float* __restrict__ kv_b, unsigned short* __restrict__ kbT)
{
    long i = (long)blockIdx.x * 256 + threadIdx.x;
    int k = i & 127, n = (i >> 7) & 511, h = i >> 16;
    kbT[i] = bf16_bits(kv_b[((long)h * 256 + k) * 512 + n]);
}

// vb[h][d(128)][r(512)] = kv_b[(h*256+128+d)*512 + r]
__global__ void pack_vb(const float* __restrict__ kv_b, unsigned short* __restrict__ vb)
{
    long i = (long)blockIdx.x * 256 + threadIdx.x;
    int r = i & 511, d = (i >> 9) & 127, h = i >> 16;
    vb[i] = bf16_bits(kv_b[((long)h * 256 + 128 + d) * 512 + r]);
}

// ---------------------------------------------------------------------------
// w = |gemm_out + bias|, in-place
// ---------------------------------------------------------------------------
__global__ void absbias_inplace(float* __restrict__ w, const float* __restrict__ b)
{
    int idx = blockIdx.x * 256 + threadIdx.x;
    if (idx < S_LEN * NH) w[idx] = fabsf(w[idx] + b[idx & 15]);
}

// ---------------------------------------------------------------------------
// In-place interleaved RoPE on ql -> index_q
// ---------------------------------------------------------------------------
__global__ void rope_iq_inplace(float* __restrict__ ql,
                                const float* __restrict__ cosb,
                                const float* __restrict__ sinb)
{
    int s = blockIdx.x, h = blockIdx.y, i = threadIdx.x;   // i in [0,64)
    float* row = ql + (long)s * (NH * IDIM) + h * IDIM;
    float y  = (i < 32) ? row[2 * i]     : row[2 * (i - 32) + 1];
    float yr = (i < 32) ? -row[2 * i + 1] : row[2 * (i - 32)];
    float c  = cosb[s * ROPE_D + i];
    float sn = sinb[s * ROPE_D + i];
    float val = y * c + yr * sn;
    __syncthreads();
    row[i] = val;
}

// ---------------------------------------------------------------------------
// In-place build of index_k from ckv rows
// ---------------------------------------------------------------------------
__global__ void build_ik_inplace(float* __restrict__ ckv,
                                 const float* __restrict__ cosb,
                                 const float* __restrict__ sinb,
                                 const float* __restrict__ knw)
{
    int k = blockIdx.x, i = threadIdx.x;   // i in [0,64)
    float* row = ckv + (long)k * IDIM;
    float y  = (i < 32) ? row[2 * i]     : row[2 * (i - 32) + 1];
    float yr = (i < 32) ? -row[2 * i + 1] : row[2 * (i - 32)];
    float c  = cosb[k * ROPE_D + i];
    float sn = sinb[k * ROPE_D + i];
    float rot = y * c + yr * sn;
    float xp = row[ROPE_D + i];
    float ss = xp * xp;
    for (int off = 32; off; off >>= 1) ss += __shfl_down(ss, off, 64);
    ss = __shfl(ss, 0, 64);
    float nv = xp * rsqrtf(ss / 64.f + 1e-6f) * knw[i];
    __syncthreads();
    row[i] = rot;
    row[ROPE_D + i] = nv;
}

// ---------------------------------------------------------------------------
// Split-bf16 MFMA GEMM: C(fp32) = A @ B^T, A,B given as (hi,lo) bf16 pairs.
// v9: B hi/lo tiles staged in LDS (scores_mfma's verified [64][136] pattern)
// — removes the 4x redundant per-wave B traffic from L2. K must be %128.
// LDS 34,816B -> 4 blocks/CU.
// ---------------------------------------------------------------------------
__global__ __launch_bounds__(256)
void gemm_split3(const unsigned short* __restrict__ Ah, const unsigned short* __restrict__ Al,
                 const unsigned short* __restrict__ Bh, const unsigned short* __restrict__ Bl,
                 float* __restrict__ C, int N, int K, int lda, int ldb, int ldc)
{
    __shared__ __align__(16) unsigned short Bhs[64][136];
    __shared__ __align__(16) unsigned short Bls[64][136];
    int tid = threadIdx.x, wv = tid >> 6, ln = tid & 63, g = ln >> 4, lo = ln & 15;
    int m0 = blockIdx.y * 64 + wv * 16, n0 = blockIdx.x * 64;
    f32x4 acc[4] = {};
    for (int k0 = 0; k0 < K; k0 += 128) {
        __syncthreads();
        for (int i = tid; i < 64 * 16; i += 256) {
            int r = i >> 4, c8 = i & 15;
            *(u16x8*)&Bhs[r][c8 * 8] = *(const u16x8*)&Bh[(long)(n0 + r) * ldb + k0 + c8 * 8];
            *(u16x8*)&Bls[r][c8 * 8] = *(const u16x8*)&Bl[(long)(n0 + r) * ldb + k0 + c8 * 8];
        }
        __syncthreads();
        #pragma unroll
        for (int kc = 0; kc < 128; kc += 32) {
            long aoff = (long)(m0 + lo) * lda + k0 + kc + g * 8;
            s16x8 ah = *(const s16x8*)&Ah[aoff];
            s16x8 al = *(const s16x8*)&Al[aoff];
            #pragma unroll
            for (int nt = 0; nt < 4; nt++) {
                s16x8 bh = *(const s16x8*)&Bhs[nt * 16 + lo][kc + g * 8];
                s16x8 bl = *(const s16x8*)&Bls[nt * 16 + lo][kc + g * 8];
                acc[nt] = __builtin_amdgcn_mfma_f32_16x16x32_bf16(ah, bh, acc[nt], 0, 0, 0);
                acc[nt] = __builtin_amdgcn_mfma_f32_16x16x32_bf16(ah, bl, acc[nt], 0, 0, 0);
                acc[nt] = __builtin_amdgcn_mfma_f32_16x16x32_bf16(al, bh, acc[nt], 0, 0, 0);
            }
        }
    }
    #pragma unroll
    for (int nt = 0; nt < 4; nt++)
        #pragma unroll
        for (int r = 0; r < 4; r++)
            C[(long)(m0 + g * 4 + r) * ldc + n0 + nt * 16 + lo] = acc[nt][r];
}

// ---------------------------------------------------------------------------
// Plain bf16 MFMA GEMM: C = A @ B^T. K explicit (lda may exceed K).
// ---------------------------------------------------------------------------
template<typename TC>
__global__ __launch_bounds__(256)
void gemm_bf16(const unsigned short* __restrict__ A, const unsigned short* __restrict__ B,
               TC* __restrict__ C, int K, int lda, int ldb, int ldc,
               long sA, long sB, long sC)
{
    A += (long)blockIdx.z * sA; B += (long)blockIdx.z * sB; C += (long)blockIdx.z * sC;
    int tid = threadIdx.x, wv = tid >> 6, ln = tid & 63, g = ln >> 4, lo = ln & 15;
    int m0 = blockIdx.y * 64 + wv * 16, n0 = blockIdx.x * 64;
    f32x4 acc[4] = {};
    for (int kc = 0; kc < K; kc += 32) {
        s16x8 a = *(const s16x8*)&A[(long)(m0 + lo) * lda + kc + g * 8];
        #pragma unroll
        for (int nt = 0; nt < 4; nt++) {
            s16x8 b = *(const s16x8*)&B[(long)(n0 + nt * 16 + lo) * ldb + kc + g * 8];
            acc[nt] = __builtin_amdgcn_mfma_f32_16x16x32_bf16(a, b, acc[nt], 0, 0, 0);
        }
    }
    #pragma unroll
    for (int nt = 0; nt < 4; nt++)
        #pragma unroll
        for (int r = 0; r < 4; r++)
            C[(long)(m0 + g * 4 + r) * ldc + n0 + nt * 16 + lo] = (TC)acc[nt][r];
}

// ---------------------------------------------------------------------------
// Indexer scores via split-bf16 MFMA.
// ---------------------------------------------------------------------------
__global__ __launch_bounds__(256)
void scores_mfma(const unsigned short* __restrict__ iq_hi, const unsigned short* __restrict__ iq_lo,
                 const unsigned short* __restrict__ ik_hi, const unsigned short* __restrict__ ik_lo,
                 const float* __restrict__ w, float* __restrict__ sc)
{
    int bk = blockIdx.x, bq = blockIdx.y;
    if (bk > bq) return;
    int q0 = bq * 64, k0 = bk * 64;
    __shared__ __align__(16) unsigned short Khi[64][136];
    __shared__ __align__(16) unsigned short Klo[64][136];
    __shared__ float Ws[64][17];
    int tid = threadIdx.x, wv = tid >> 6, ln = tid & 63, g = ln >> 4, lo = ln & 15;

    for (int i = tid; i < 64 * 16; i += 256) {
        int r = i >> 4, c8 = i & 15;
        *(u16x8*)&Khi[r][c8 * 8] = *(const u16x8*)&ik_hi[(long)(k0 + r) * IDIM + c8 * 8];
        *(u16x8*)&Klo[r][c8 * 8] = *(const u16x8*)&ik_lo[(long)(k0 + r) * IDIM + c8 * 8];
    }
    for (int i = tid; i < 64 * 16; i += 256)
        Ws[i >> 4][i & 15] = w[(long)(q0 + (i >> 4)) * NH + (i & 15)];
    __syncthreads();

    float fin[4][4][4] = {};   // [mt][nt][r]
    #pragma unroll
    for (int hh = 0; hh < 4; hh++) {
        int h = wv * 4 + hh;
        #pragma unroll
        for (int mg = 0; mg < 2; mg++) {
            f32x4 acc[2][4] = {};
            #pragma unroll
            for (int kc = 0; kc < 4; kc++) {
                s16x8 ah[2], al[2];
                #pragma unroll
                for (int mi = 0; mi < 2; mi++) {
                    long off = ((long)(q0 + (mg * 2 + mi) * 16 + lo) * NH + h) * IDIM + kc * 32 + g * 8;
                    ah[mi] = *(const s16x8*)&iq_hi[off];
                    al[mi] = *(const s16x8*)&iq_lo[off];
                }
                #pragma unroll
                for (int nt = 0; nt < 4; nt++) {
                    s16x8 bh = *(const s16x8*)&Khi[nt * 16 + lo][kc * 32 + g * 8];
                    s16x8 bl = *(const s16x8*)&Klo[nt * 16 + lo][kc * 32 + g * 8];
                    #pragma unroll
                    for (int mi = 0; mi < 2; mi++) {
                        acc[mi][nt] = __builtin_amdgcn_mfma_f32_16x16x32_bf16(ah[mi], bh, acc[mi][nt], 0, 0, 0);
                        acc[mi][nt] = __builtin_amdgcn_mfma_f32_16x16x32_bf16(ah[mi], bl, acc[mi][nt], 0, 0, 0);
                        acc[mi][nt] = __builtin_amdgcn_mfma_f32_16x16x32_bf16(al[mi], bh, acc[mi][nt], 0, 0, 0);
                    }
                }
            }
            #pragma unroll
            for (int mi = 0; mi < 2; mi++) {
                int mt = mg * 2 + mi;
                #pragma unroll
                for (int r = 0; r < 4; r++) {
                    float wqh = Ws[mt * 16 + g * 4 + r][h];
                    #pragma unroll
                    for (int nt = 0; nt < 4; nt++) {
                        float v = acc[mi][nt][r] * SCALING;
                        v = v > 0.f ? v : 0.f;
                        fin[mt][nt][r] += v * wqh;
                    }
                }
            }
        }
    }
    __syncthreads();
    float (*FinBuf)[68] = (float(*)[68])&Khi[0][0];
    for (int wt = 0; wt < 4; wt++) {
        if (wv == wt) {
            #pragma unroll
            for (int mt = 0; mt < 4; mt++)
                #pragma unroll
                for (int r = 0; r < 4; r++)
                    #pragma unroll
                    for (int nt = 0; nt < 4; nt++) {
                        if (wt == 0) FinBuf[mt * 16 + g * 4 + r][nt * 16 + lo] = fin[mt][nt][r];
                        else         FinBuf[mt * 16 + g * 4 + r][nt * 16 + lo] += fin[mt][nt][r];
                    }
        }
        __syncthreads();
    }
    for (int i = tid; i < 64 * 16; i += 256) {
        int r = i >> 4, c4 = i & 15;
        *(f32x4*)&sc[(long)(q0 + r) * S_LEN + k0 + c4 * 4] = *(f32x4*)&FinBuf[r][c4 * 4];
    }
}

// ---------------------------------------------------------------------------
// Exact top-1024 per row via radix-select on float bits (scores >= 0).
// ---------------------------------------------------------------------------
__device__ __forceinline__ int block_scan_excl(int v, volatile int* lds, int tid, int* total)
{
    lds[tid] = v;
    __syncthreads();
    int x = v;
    for (int off = 1; off < 256; off <<= 1) {
        int y = (tid >= off) ? lds[tid - off] : 0;
        __syncthreads();
        x += y;
        lds[tid] = x;
        __syncthreads();
    }
    int t = lds[255];
    __syncthreads();
    *total = t;
    return x - v;
}

__global__ __launch_bounds__(256)
void topk_kernel(const float* __restrict__ sc, int* __restrict__ sel_idx)
{
    __shared__ int lds[256];
    __shared__ int wsum[4];
    int q = blockIdx.x, tid = threadIdx.x;
    int n = q + 1;
    int* row_sel = sel_idx + (long)q * TOPK_K;
    if (n <= TOPK_K) {
        for (int i = tid; i < n; i += 256) row_sel[i] = i;
        return;
    }
    const float* row = sc + (long)q * S_LEN;
    unsigned bits[8];
    int base = tid * 8;
    #pragma unroll
    for (int i = 0; i < 8; i++) {
        int k = base + i;
        bits[i] = (k < n) ? __float_as_uint(row[k]) : 0u;
    }
    unsigned prefix = 0;
    for (int bit = 30; bit >= 0; bit--) {
        unsigned cand = prefix | (1u << bit);
        int c = 0;
        #pragma unroll
        for (int i = 0; i < 8; i++) c += (bits[i] >= cand) ? 1 : 0;
        for (int off = 32; off; off >>= 1) c += __shfl_down(c, off, 64);
        if ((tid & 63) == 0) wsum[tid >> 6] = c;
        __syncthreads();
        int total = wsum[0] + wsum[1] + wsum[2] + wsum[3];
        __syncthreads();
        if (total >= TOPK_K) prefix = cand;
    }
    unsigned v = prefix;
    int lgt = 0, leq = 0;
    #pragma unroll
    for (int i = 0; i < 8; i++) {
        int k = base + i;
        if (k >= n) break;
        if (bits[i] > v) lgt++;
        else if (bits[i] == v) leq++;
    }
    int tot_gt, tot_eq;
    int gt_off = block_scan_excl(lgt, lds, tid, &tot_gt);
    int eq_off = block_scan_excl(leq, lds, tid, &tot_eq);
    int fill = TOPK_K - tot_gt;
    int gpos = gt_off, epos = eq_off;
    for (int i = 0; i < 8; i++) {
        int k = base + i;
        if (k >= n) break;
        if (bits[i] > v) {
            row_sel[gpos++] = k;
        } else if (bits[i] == v) {
            if (epos < fill) row_sel[tot_gt + epos] = k;
            epos++;
        }
    }
}

// ---------------------------------------------------------------------------
// bf16 packs for the attention path
// ---------------------------------------------------------------------------
__global__ void pack_kv(const float* __restrict__ k_pass, const float* __restrict__ k_rot,
                        __hip_bfloat16* __restrict__ kvb)
{
    int k = blockIdx.x;
    for (int i = threadIdx.x; i < CDIM; i += 256) {
        float v = (i < KV_LORA) ? k_pass[(long)k * KV_LORA + i]
                                : k_rot[(long)k * ROPE_D + (i - KV_LORA)];
        kvb[(long)k * CDIM + i] = __float2bfloat16(v);
    }
}

__global__ void pack_qrot(const float* __restrict__ q_rot, __hip_bfloat16* __restrict__ Qcat)
{
    int q = blockIdx.x;
    for (int j = threadIdx.x; j < NH * ROPE_D; j += 256) {
        int h = j >> 6, i = j & 63;
        Qcat[((long)q * NH + h) * CDIM + KV_LORA + i] =
            __float2bfloat16(q_rot[((long)h * S_LEN + q) * ROPE_D + i]);
    }
}

// ---------------------------------------------------------------------------
// MLA sparse attention v9: v7 (verified, 304us) + XOR half-bit bank swizzle.
// Unified LDS layout:
//   byte(key 0..31, D 0..575) = (D>>4)*1024 + key*32
//                             + (((D>>3)&1) ^ ((key>>3)&1))*16 + (D&7)*2
// All three access patterns keep their v7 instruction forms (b128 staging
// writes, b128 S reads, scalar u16 PV reads); only the 16B-half selector
// gains the ^(key>>3) bit. Effect: PV's 4 g-lane-groups (which aliased one
// bank at stride 32B) split across 2 bank-sets -> 4-way -> 2-way (free).
// Everything else byte-identical to v7.
// ---------------------------------------------------------------------------
__global__ __launch_bounds__(256, 2)
void attn_mla9(const __hip_bfloat16* __restrict__ Qcat,
               const __hip_bfloat16* __restrict__ kvb,
               const int* __restrict__ sel_idx,
               unsigned short* __restrict__ Oout)   // == (unsigned short*)Qcat
{
    __shared__ __align__(16) unsigned int Kb[2][9216];   // 2 x 36,864 B
    __shared__ __align__(16) float Sp[4][64][4];         // 4,096 B partial-S

    const int q   = blockIdx.x;
    const int tid = threadIdx.x;
    const int wv  = tid >> 6;            // wave 0..3
    const int ln  = tid & 63;
    const int g   = ln >> 4, lo = ln & 15;
    const int kh  = wv >> 1, dh = wv & 1;   // S-split: key-half, dim-half
    const int k_l = ln >> 2, oct = ln & 3;  // staging roles
    const int cnt = (q + 1 < TOPK_K) ? (q + 1) : TOPK_K;
    const int* sel = sel_idx + (long)q * TOPK_K;
    const unsigned short* kvu = (const unsigned short*)kvb;
    const unsigned short* qrow = (const unsigned short*)Qcat + (long)q * NH * CDIM;

    // Q frags for this wave's 9 S-chunks (dims dh*288 + cc*32 + g*8)
    s16x8 Qf[9];
    #pragma unroll
    for (int cc = 0; cc < 9; cc++)
        Qf[cc] = *(const s16x8*)&qrow[lo * CDIM + (dh * 9 + cc) * 32 + g * 8];

    float m_run = -1e30f, l_run = 0.f;
    f32x4 O[8];
    #pragma unroll
    for (int s = 0; s < 8; s++) O[s] = (f32x4){0.f, 0.f, 0.f, 0.f};

    const int ntl = (cnt + 31) >> 5;

    // staging: unit u = wv*9+uu, khu = u&1 (key-half), cu = u>>1 (32-dim chunk)
    // lane gathers key khu*16+k_l, dims cu*32 + oct*8 .. +8 (16B)
    // LDS byte = (cu*2+(oct>>1))*1024 + key*32 + ((oct&1)^(k_l>>3))*16
    const int wsl16 = (((oct & 1) ^ (k_l >> 3)) << 4);

    // ---- prologue: stage tile 0 ----
    f32x4 Vst[9];
    int i0 = ln & 31;
    int selvA = sel[i0 < cnt ? i0 : cnt - 1];
    #pragma unroll
    for (int uu = 0; uu < 9; uu++) {
        int u = wv * 9 + uu, khu = u & 1, cu = u >> 1;
        int row = __shfl(selvA, khu * 16 + k_l, 64);
        Vst[uu] = *(const f32x4*)(kvu + (long)row * CDIM + cu * 32 + oct * 8);
    }
    #pragma unroll
    for (int uu = 0; uu < 9; uu++) {
        int u = wv * 9 + uu, khu = u & 1, cu = u >> 1;
        int byte = (cu * 2 + (oct >> 1)) * 1024 + (khu * 16 + k_l) * 32 + wsl16;
        *(f32x4*)((char*)&Kb[0][0] + byte) = Vst[uu];
    }
    int i1 = 32 + (ln & 31);
    int selvN = sel[i1 < cnt ? i1 : cnt - 1];
    __syncthreads();

    // S-read lane base: byte(key=kh*16+lo, D=c*32+g*8)
    //   = ((c*4+g)>>1)*1024 + (kh*16+lo)*32 + ((g&1)^(lo>>3))*16
    const int sread_key = (kh * 16 + lo) * 32 + ((((g & 1) ^ (lo >> 3)) & 1) << 4);
    const int idxA = (g & 1) * 32 + lo;   // pa-shuffle source lanes
    const int idxB = idxA + 16;
    int cur = 0;

    for (int t = 0; t < ntl; t++) {
        const int kb = t * 32;
        const bool hasn = (t + 1 < ntl);

        // --- issue next tile's gathers (fly over this tile's compute)
        if (hasn) {
            #pragma unroll
            for (int uu = 0; uu < 9; uu++) {
                int u = wv * 9 + uu, khu = u & 1, cu = u >> 1;
                int row = __shfl(selvN, khu * 16 + k_l, 64);
                Vst[uu] = *(const f32x4*)(kvu + (long)row * CDIM + cu * 32 + oct * 8);
            }
        }
        int ni = kb + 64 + (ln & 31);
        int selvNN = sel[ni < cnt ? ni : cnt - 1];

        // --- S partial: 9 chunks (this wave's dims), keys kh*16..+16
        const char* Kc = (const char*)&Kb[cur][0];
        f32x4 Sacc = (f32x4){0.f, 0.f, 0.f, 0.f};
        #pragma unroll
        for (int cc = 0; cc < 9; cc++) {
            int c = dh * 9 + cc;
            s16x8 av = *(const s16x8*)(Kc + ((c * 4 + g) >> 1) * 1024 + sread_key);
            Sacc = __builtin_amdgcn_mfma_f32_16x16x32_bf16(av, Qf[cc], Sacc, 0, 0, 0);
        }
        *(f32x4*)&Sp[wv][ln][0] = Sacc;
        __syncthreads();   // sync1: partials ready

        f32x4 S0 = *(const f32x4*)&Sp[0][ln][0];
        { f32x4 tmp = *(const f32x4*)&Sp[1][ln][0]; S0 += tmp; }
        f32x4 S1 = *(const f32x4*)&Sp[2][ln][0];
        { f32x4 tmp = *(const f32x4*)&Sp[3][ln][0]; S1 += tmp; }

        // --- online softmax over 32 keys (head = lo, replicated across quads)
        float pv[8];
        float mx = -1e30f;
        #pragma unroll
        for (int r = 0; r < 4; r++) {
            float s = S0[r] * SCALING;
            if (kb + g * 4 + r >= cnt) s = -1e30f;
            pv[r] = s;
            mx = fmaxf(mx, s);
        }
        #pragma unroll
        for (int r = 0; r < 4; r++) {
            float s = S1[r] * SCALING;
            if (kb + 16 + g * 4 + r >= cnt) s = -1e30f;
            pv[4 + r] = s;
            mx = fmaxf(mx, s);
        }
        mx = fmaxf(mx, __shfl_xor(mx, 16, 64));
        mx = fmaxf(mx, __shfl_xor(mx, 32, 64));
        float mn = fmaxf(m_run, mx);
        float al = __expf(m_run - mn);
        float sum = 0.f;
        #pragma unroll
        for (int j = 0; j < 8; j++) { float e = __expf(pv[j] - mn); pv[j] = e; sum += e; }
        sum += __shfl_xor(sum, 16, 64);
        sum += __shfl_xor(sum, 32, 64);
        m_run = mn;
        l_run = l_run * al + sum;

        // --- pa frag in-register: W[a][c] = pack(pv[a*4+2c], pv[a*4+2c+1])
        int W00 = (int)((unsigned)bf16_bits(pv[0]) | ((unsigned)bf16_bits(pv[1]) << 16));
        int W01 = (int)((unsigned)bf16_bits(pv[2]) | ((unsigned)bf16_bits(pv[3]) << 16));
        int W10 = (int)((unsigned)bf16_bits(pv[4]) | ((unsigned)bf16_bits(pv[5]) << 16));
        int W11 = (int)((unsigned)bf16_bits(pv[6]) | ((unsigned)bf16_bits(pv[7]) << 16));
        int A0 = __shfl(W00, idxA, 64), A1 = __shfl(W01, idxA, 64);
        int A2 = __shfl(W00, idxB, 64), A3 = __shfl(W01, idxB, 64);
        int B0 = __shfl(W10, idxA, 64), B1 = __shfl(W11, idxA, 64);
        int B2 = __shfl(W10, idxB, 64), B3 = __shfl(W11, idxB, 64);
        i32x4 paw;
        paw[0] = (g < 2) ? A0 : B0;
        paw[1] = (g < 2) ? A1 : B1;
        paw[2] = (g < 2) ? A2 : B2;
        paw[3] = (g < 2) ? A3 : B3;
        s16x8 pa = __builtin_bit_cast(s16x8, paw);

        // --- rescale O by per-head alpha (head = g*4+r)
        float alh[4];
        #pragma unroll
        for (int r = 0; r < 4; r++) alh[r] = __shfl(al, g * 4 + r, 64);
        #pragma unroll
        for (int s = 0; s < 8; s++) {
            O[s][0] *= alh[0]; O[s][1] *= alh[1]; O[s][2] *= alh[2]; O[s][3] *= alh[3];
        }

        // --- PV: this wave's 128 output dims; B-frags via scalar LDS reads
        // lane (lo,g): keys g*8+j at dim D = wv*128 + s*16 + lo
        // byte = (wv*8+s)*1024 + (g*8+j)*32 + ((lo>>3)^(g&1))*16 + (lo&7)*2
        const char* Kpv = Kc + wv * 8192 + g * 256 +
                          ((((lo >> 3) ^ (g & 1)) & 1) << 4) + (lo & 7) * 2;
        #pragma unroll
        for (int s = 0; s < 8; s++) {
            const char* bs = Kpv + s * 1024;
            s16x8 bv;
            #pragma unroll
            for (int j = 0; j < 8; j++)
                bv[j] = *(const short*)(bs + j * 32);
            O[s] = __builtin_amdgcn_mfma_f32_16x16x32_bf16(pa, bv, O[s], 0, 0, 0);
        }

        // --- commit next tile (compiler inserts vmcnt wait for Vst here)
        if (hasn) {
            char* Kn = (char*)&Kb[cur ^ 1][0];
            #pragma unroll
            for (int uu = 0; uu < 9; uu++) {
                int u = wv * 9 + uu, khu = u & 1, cu = u >> 1;
                int byte = (cu * 2 + (oct >> 1)) * 1024 + (khu * 16 + k_l) * 32 + wsl16;
                *(f32x4*)(Kn + byte) = Vst[uu];
            }
        }
        __syncthreads();   // sync2: staging done, Kb[cur]/Sp fully consumed
        cur ^= 1;
        selvN = selvNN;
    }

    // --- epilogue: O / l -> bf16, wave's own 128-dim slice of the Qcat row
    float linv[4];
    #pragma unroll
    for (int r = 0; r < 4; r++) linv[r] = 1.f / __shfl(l_run, g * 4 + r, 64);
    unsigned short* orow = Oout + (long)q * NH * CDIM;
    #pragma unroll
    for (int s = 0; s < 8; s++)
        #pragma unroll
        for (int r = 0; r < 4; r++)
            orow[(g * 4 + r) * KV_LORA + wv * 128 + s * 16 + lo] = bf16_bits(O[s][r] * linv[r]);
}

// ---------------------------------------------------------------------------
// Launch
// ---------------------------------------------------------------------------
extern "C" void kernel_launch(void* const* d_in, const int* in_sizes, int n_in,
                              void* d_out, int out_size, void* d_ws, size_t ws_size,
                              hipStream_t stream)
{
    const float* q_latent = (const float*)d_in[0];   // (2048,1536)
    const float* hidden   = (const float*)d_in[1];   // (2048,2048)
    const float* cosp     = (const float*)d_in[2];   // (2048,64)
    const float* sinp     = (const float*)d_in[3];   // (2048,64)
    const float* q_pass   = (const float*)d_in[4];   // (16,2048,128)
    const float* q_rot    = (const float*)d_in[5];   // (16,2048,64)
    const float* k_pass   = (const float*)d_in[6];   // (2048,512)
    const float* k_rot    = (const float*)d_in[7];   // (2048,64)
    const float* kv_b     = (const float*)d_in[9];   // (4096,512)
    const float* wq_b_w   = (const float*)d_in[10];  // (2048,1536)
    const float* wk_w     = (const float*)d_in[11];  // (128,2048)
    const float* k_norm_w = (const float*)d_in[12];  // (64)
    const float* wproj_w  = (const float*)d_in[13];  // (16,2048)
    const float* wproj_b  = (const float*)d_in[14];  // (16)

    float* ws = (float*)d_ws;
    // Persistent: sel_idx
    int* sel_idx = (int*)ws;                                       // [0 .. 2,097,152)
    // Phase 1a: split inputs for ql GEMM
    unsigned short* qlat_hi = (unsigned short*)(ws + 2097152);
    unsigned short* qlat_lo = (unsigned short*)(ws + 3670016);
    unsigned short* wq_hi   = (unsigned short*)(ws + 5242880);
    unsigned short* wq_lo   = (unsigned short*)(ws + 6815744);     // ends 8,388,608 f
    float* ql = ws + 8388608;                                      // 4,194,304 f -> 12,582,912
    // Phase 1b (after ql GEMM; aliases qlat/wq region):
    unsigned short* iq_hi = (unsigned short*)(ws + 2097152);
    unsigned short* iq_lo = (unsigned short*)(ws + 4194304);
    unsigned short* ik_hi = (unsigned short*)(ws + 6291456);
    unsigned short* ik_lo = (unsigned short*)(ws + 6422528);
    float* wmat = ws + 6553600;                                    // 32,768 f
    float* ckv  = ws + 6586368;                                    // 262,144 f -> 6,848,512
    float* sc   = ws + 8388608;                                    // aliases ql (dead after pack iq)
    float* part = ws + 12582912;                                   // 2,359,296 f -> 14,942,208 (phase 1 only)
    // Phase 2 (after topk; aliases phase-1):
    __hip_bfloat16* Qcat = (__hip_bfloat16*)(ws + 2097152);        // ends f-off 11,534,336; O written in-place
    __hip_bfloat16* kvb  = (__hip_bfloat16*)(ws + 11534336);       // -> 12,124,160
    unsigned short* kbT  = (unsigned short*)(ws + 12124160);       // -> 12,648,448
    unsigned short* vb   = (unsigned short*)(ws + 12648448);       // -> 13,172,736
    unsigned short* qp   = (unsigned short*)(ws + 13172736);       // -> 15,269,888  (61.1 MB peak)

    dim3 b256(256);
    // --- indexer path (split-bf16 MFMA, selection-exact) ---
    pack_split<<<dim3(12288), b256, 0, stream>>>(q_latent, qlat_hi, qlat_lo, 2048L * 1536);
    pack_split<<<dim3(12288), b256, 0, stream>>>(wq_b_w, wq_hi, wq_lo, 2048L * 1536);
    gemm_split3<<<dim3(32, 32), b256, 0, stream>>>(qlat_hi, qlat_lo, wq_hi, wq_lo,
        ql, 2048, 1536, 1536, 1536, 2048);
    rope_iq_inplace<<<dim3(2048, 16), dim3(64), 0, stream>>>(ql, cosp, sinp);
    pack_split<<<dim3(16384), b256, 0, stream>>>(ql, iq_hi, iq_lo, 2048L * 2048);
    proj_splitk<<<dim3(3, 32, 8), b256, 0, stream>>>(hidden, wk_w, wproj_w, part);
    proj_reduce<<<dim3((S_LEN * 144 + 255) / 256), b256, 0, stream>>>(part, ckv, wmat);
    build_ik_inplace<<<dim3(2048), dim3(64), 0, stream>>>(ckv, cosp, sinp, k_norm_w);
    pack_split<<<dim3(1024), b256, 0, stream>>>(ckv, ik_hi, ik_lo, 2048L * 128);
    absbias_inplace<<<dim3(128), b256, 0, stream>>>(wmat, wproj_b);
    scores_mfma<<<dim3(32, 32), b256, 0, stream>>>(iq_hi, iq_lo, ik_hi, ik_lo, wmat, sc);
    topk_kernel<<<dim3(2048), b256, 0, stream>>>(sc, sel_idx);

    // --- attention path (bf16 MFMA, compressed space) ---
    pack_bf16<<<dim3(16384), b256, 0, stream>>>(q_pass, qp, 16L * 2048 * 128);
    pack_kbT<<<dim3(4096), b256, 0, stream>>>(kv_b, kbT);
    pack_vb<<<dim3(4096), b256, 0, stream>>>(kv_b, vb);
    pack_kv<<<dim3(2048), b256, 0, stream>>>(k_pass, k_rot, kvb);
    // q_abs[h] = qp[h] (2048x128) @ kbT[h]^T (512x128): K=128 -> Qcat[:, h, 0:512]
    gemm_bf16<__hip_bfloat16><<<dim3(8, 32, 16), b256, 0, stream>>>(
        qp, kbT, (__hip_bfloat16*)Qcat, 128, 128, 128, NH * CDIM,
        2048L * 128, 512L * 128, (long)CDIM);
    pack_qrot<<<dim3(2048), b256, 0, stream>>>(q_rot, Qcat);

    // Work-split pipelined attention, XOR-swizzled LDS tile.
    attn_mla9<<<dim3(2048), dim3(256), 0, stream>>>(Qcat, kvb, sel_idx,
                                                    (unsigned short*)Qcat);
    // out[q][h][d] = O[q][h][:512] . vb[h][d][:512]; O rows live inside Qcat
    // (row stride NH*CDIM=9216, head offset h*512).
    gemm_bf16<float><<<dim3(2, 32, 16), b256, 0, stream>>>(
        (const unsigned short*)Qcat, vb, (float*)d_out,
        512, NH * CDIM, KV_LORA, NH * IDIM,
        512L, 128L * 512, (long)IDIM);
}

// Round 9
// 739.875 us; speedup vs baseline: 1.2692x; 1.0614x over previous
//
#include <hip/hip_runtime.h>
#include <hip/hip_bf16.h>

// Problem constants (B=1)
#define S_LEN   2048
#define NH      16
#define ROPE_D  64
#define IDIM    128
#define KV_LORA 512
#define CDIM    576            // KV_LORA + ROPE_D (compressed attention dim)
#define TOPK_K  1024
#define SCALING 0.08838834764831845f   // 128^-0.5

typedef __attribute__((ext_vector_type(4))) float f32x4;
typedef __attribute__((ext_vector_type(8))) short s16x8;
typedef __attribute__((ext_vector_type(4))) int   i32x4;
typedef __attribute__((ext_vector_type(8))) unsigned short u16x8;

static __device__ __forceinline__ unsigned short bf16_bits(float v)
{
    __hip_bfloat16 h = __float2bfloat16(v);
    return *(unsigned short*)&h;
}

#define BM 64
#define BN 64
#define BK 16

// ---------------------------------------------------------------------------
// Fused split-K projection: part[ks][m][n] = hidden[m, ks*256:+256] @ W^T
// ---------------------------------------------------------------------------
#define PKC 256

__global__ __launch_bounds__(256)
void proj_splitk(const float* __restrict__ hidden, const float* __restrict__ wk_w,
                 const float* __restrict__ wproj_w, float* __restrict__ part)
{
    int nt = blockIdx.x, mt = blockIdx.y, ks = blockIdx.z;
    int n0 = nt * 64, m0 = mt * 64, k00 = ks * PKC;
    __shared__ float As[BK][BM + 1];
    __shared__ float Bs[BK][BN + 1];
    int tid = threadIdx.x, tx = tid & 15, ty = tid >> 4;
    float acc[4][4] = {};
    for (int k0 = 0; k0 < PKC; k0 += BK) {
        for (int t = tid; t < BM * BK; t += 256) {
            int m = t >> 4, kk = t & 15;
            As[kk][m] = hidden[(long)(m0 + m) * 2048 + k00 + k0 + kk];
        }
        for (int t = tid; t < BN * BK; t += 256) {
            int nn = t >> 4, kk = t & 15;
            int n = n0 + nn;
            float v = 0.f;
            if (n < 128)      v = wk_w[(long)n * 2048 + k00 + k0 + kk];
            else if (n < 144) v = wproj_w[(long)(n - 128) * 2048 + k00 + k0 + kk];
            Bs[kk][nn] = v;
        }
        __syncthreads();
        #pragma unroll
        for (int kk = 0; kk < BK; kk++) {
            float a[4], b[4];
            #pragma unroll
            for (int i = 0; i < 4; i++) a[i] = As[kk][ty * 4 + i];
            #pragma unroll
            for (int j = 0; j < 4; j++) b[j] = Bs[kk][tx * 4 + j];
            #pragma unroll
            for (int i = 0; i < 4; i++)
                #pragma unroll
                for (int j = 0; j < 4; j++) acc[i][j] += a[i] * b[j];
        }
        __syncthreads();
    }
    for (int i = 0; i < 4; i++) {
        int m = m0 + ty * 4 + i;
        for (int j = 0; j < 4; j++) {
            int n = n0 + tx * 4 + j;
            if (n < 144) part[((long)ks * S_LEN + m) * 144 + n] = acc[i][j];
        }
    }
}

__global__ void proj_reduce(const float* __restrict__ part, float* __restrict__ ckv,
                            float* __restrict__ wmat)
{
    int i = blockIdx.x * 256 + threadIdx.x;
    if (i >= S_LEN * 144) return;
    int m = i / 144, n = i % 144;
    float s = 0.f;
    #pragma unroll
    for (int ks = 0; ks < 8; ks++) s += part[((long)ks * S_LEN + m) * 144 + n];
    if (n < 128) ckv[(long)m * 128 + n] = s;
    else         wmat[(long)m * 16 + (n - 128)] = s;
}

// ---------------------------------------------------------------------------
// Elementwise packs
// ---------------------------------------------------------------------------
__global__ void pack_split(const float* __restrict__ x, unsigned short* __restrict__ hi,
                           unsigned short* __restrict__ lo, long n)
{
    long i = (long)blockIdx.x * 256 + threadIdx.x;
    if (i < n) {
        float v = x[i];
        __hip_bfloat16 h = __float2bfloat16(v);
        float hv = __bfloat162float(h);
        hi[i] = *(unsigned short*)&h;
        lo[i] = bf16_bits(v - hv);
    }
}

__global__ void pack_bf16(const float* __restrict__ x, unsigned short* __restrict__ y, long n)
{
    long i = (long)blockIdx.x * 256 + threadIdx.x;
    if (i < n) y[i] = bf16_bits(x[i]);
}

// kbT[h][n(512)][k(128)] = kv_b[(h*256 + k)*512 + n]
__global__ void pack_kbT(const float* __restrict__ kv_b, unsigned short* __restrict__ kbT)
{
    long i = (long)blockIdx.x * 256 + threadIdx.x;
    int k = i & 127, n = (i >> 7) & 511, h = i >> 16;
    kbT[i] = bf16_bits(kv_b[((long)h * 256 + k) * 512 + n]);
}

// vb[h][d(128)][r(512)] = kv_b[(h*256+128+d)*512 + r]
__global__ void pack_vb(const float* __restrict__ kv_b, unsigned short* __restrict__ vb)
{
    long i = (long)blockIdx.x * 256 + threadIdx.x;
    int r = i & 511, d = (i >> 9) & 127, h = i >> 16;
    vb[i] = bf16_bits(kv_b[((long)h * 256 + 128 + d) * 512 + r]);
}

// ---------------------------------------------------------------------------
// w = |gemm_out + bias|, in-place
// ---------------------------------------------------------------------------
__global__ void absbias_inplace(float* __restrict__ w, const float* __restrict__ b)
{
    int idx = blockIdx.x * 256 + threadIdx.x;
    if (idx < S_LEN * NH) w[idx] = fabsf(w[idx] + b[idx & 15]);
}

// ---------------------------------------------------------------------------
// In-place interleaved RoPE on ql -> index_q
// ---------------------------------------------------------------------------
__global__ void rope_iq_inplace(float* __restrict__ ql,
                                const float* __restrict__ cosb,
                                const float* __restrict__ sinb)
{
    int s = blockIdx.x, h = blockIdx.y, i = threadIdx.x;   // i in [0,64)
    float* row = ql + (long)s * (NH * IDIM) + h * IDIM;
    float y  = (i < 32) ? row[2 * i]     : row[2 * (i - 32) + 1];
    float yr = (i < 32) ? -row[2 * i + 1] : row[2 * (i - 32)];
    float c  = cosb[s * ROPE_D + i];
    float sn = sinb[s * ROPE_D + i];
    float val = y * c + yr * sn;
    __syncthreads();
    row[i] = val;
}

// ---------------------------------------------------------------------------
// In-place build of index_k from ckv rows
// ---------------------------------------------------------------------------
__global__ void build_ik_inplace(float* __restrict__ ckv,
                                 const float* __restrict__ cosb,
                                 const float* __restrict__ sinb,
                                 const float* __restrict__ knw)
{
    int k = blockIdx.x, i = threadIdx.x;   // i in [0,64)
    float* row = ckv + (long)k * IDIM;
    float y  = (i < 32) ? row[2 * i]     : row[2 * (i - 32) + 1];
    float yr = (i < 32) ? -row[2 * i + 1] : row[2 * (i - 32)];
    float c  = cosb[k * ROPE_D + i];
    float sn = sinb[k * ROPE_D + i];
    float rot = y * c + yr * sn;
    float xp = row[ROPE_D + i];
    float ss = xp * xp;
    for (int off = 32; off; off >>= 1) ss += __shfl_down(ss, off, 64);
    ss = __shfl(ss, 0, 64);
    float nv = xp * rsqrtf(ss / 64.f + 1e-6f) * knw[i];
    __syncthreads();
    row[i] = rot;
    row[ROPE_D + i] = nv;
}

// ---------------------------------------------------------------------------
// Split-bf16 MFMA GEMM: C(fp32) = A @ B^T, A,B given as (hi,lo) bf16 pairs.
// B hi/lo tiles staged in LDS (verified Round 7, ~144us total win).
// ---------------------------------------------------------------------------
__global__ __launch_bounds__(256)
void gemm_split3(const unsigned short* __restrict__ Ah, const unsigned short* __restrict__ Al,
                 const unsigned short* __restrict__ Bh, const unsigned short* __restrict__ Bl,
                 float* __restrict__ C, int N, int K, int lda, int ldb, int ldc)
{
    __shared__ __align__(16) unsigned short Bhs[64][136];
    __shared__ __align__(16) unsigned short Bls[64][136];
    int tid = threadIdx.x, wv = tid >> 6, ln = tid & 63, g = ln >> 4, lo = ln & 15;
    int m0 = blockIdx.y * 64 + wv * 16, n0 = blockIdx.x * 64;
    f32x4 acc[4] = {};
    for (int k0 = 0; k0 < K; k0 += 128) {
        __syncthreads();
        for (int i = tid; i < 64 * 16; i += 256) {
            int r = i >> 4, c8 = i & 15;
            *(u16x8*)&Bhs[r][c8 * 8] = *(const u16x8*)&Bh[(long)(n0 + r) * ldb + k0 + c8 * 8];
            *(u16x8*)&Bls[r][c8 * 8] = *(const u16x8*)&Bl[(long)(n0 + r) * ldb + k0 + c8 * 8];
        }
        __syncthreads();
        #pragma unroll
        for (int kc = 0; kc < 128; kc += 32) {
            long aoff = (long)(m0 + lo) * lda + k0 + kc + g * 8;
            s16x8 ah = *(const s16x8*)&Ah[aoff];
            s16x8 al = *(const s16x8*)&Al[aoff];
            #pragma unroll
            for (int nt = 0; nt < 4; nt++) {
                s16x8 bh = *(const s16x8*)&Bhs[nt * 16 + lo][kc + g * 8];
                s16x8 bl = *(const s16x8*)&Bls[nt * 16 + lo][kc + g * 8];
                acc[nt] = __builtin_amdgcn_mfma_f32_16x16x32_bf16(ah, bh, acc[nt], 0, 0, 0);
                acc[nt] = __builtin_amdgcn_mfma_f32_16x16x32_bf16(ah, bl, acc[nt], 0, 0, 0);
                acc[nt] = __builtin_amdgcn_mfma_f32_16x16x32_bf16(al, bh, acc[nt], 0, 0, 0);
            }
        }
    }
    #pragma unroll
    for (int nt = 0; nt < 4; nt++)
        #pragma unroll
        for (int r = 0; r < 4; r++)
            C[(long)(m0 + g * 4 + r) * ldc + n0 + nt * 16 + lo] = acc[nt][r];
}

// ---------------------------------------------------------------------------
// Plain bf16 MFMA GEMM: C = A @ B^T. K explicit (lda may exceed K).
// ---------------------------------------------------------------------------
template<typename TC>
__global__ __launch_bounds__(256)
void gemm_bf16(const unsigned short* __restrict__ A, const unsigned short* __restrict__ B,
               TC* __restrict__ C, int K, int lda, int ldb, int ldc,
               long sA, long sB, long sC)
{
    A += (long)blockIdx.z * sA; B += (long)blockIdx.z * sB; C += (long)blockIdx.z * sC;
    int tid = threadIdx.x, wv = tid >> 6, ln = tid & 63, g = ln >> 4, lo = ln & 15;
    int m0 = blockIdx.y * 64 + wv * 16, n0 = blockIdx.x * 64;
    f32x4 acc[4] = {};
    for (int kc = 0; kc < K; kc += 32) {
        s16x8 a = *(const s16x8*)&A[(long)(m0 + lo) * lda + kc + g * 8];
        #pragma unroll
        for (int nt = 0; nt < 4; nt++) {
            s16x8 b = *(const s16x8*)&B[(long)(n0 + nt * 16 + lo) * ldb + kc + g * 8];
            acc[nt] = __builtin_amdgcn_mfma_f32_16x16x32_bf16(a, b, acc[nt], 0, 0, 0);
        }
    }
    #pragma unroll
    for (int nt = 0; nt < 4; nt++)
        #pragma unroll
        for (int r = 0; r < 4; r++)
            C[(long)(m0 + g * 4 + r) * ldc + n0 + nt * 16 + lo] = (TC)acc[nt][r];
}

// ---------------------------------------------------------------------------
// Indexer scores via split-bf16 MFMA.
// ---------------------------------------------------------------------------
__global__ __launch_bounds__(256)
void scores_mfma(const unsigned short* __restrict__ iq_hi, const unsigned short* __restrict__ iq_lo,
                 const unsigned short* __restrict__ ik_hi, const unsigned short* __restrict__ ik_lo,
                 const float* __restrict__ w, float* __restrict__ sc)
{
    int bk = blockIdx.x, bq = blockIdx.y;
    if (bk > bq) return;
    int q0 = bq * 64, k0 = bk * 64;
    __shared__ __align__(16) unsigned short Khi[64][136];
    __shared__ __align__(16) unsigned short Klo[64][136];
    __shared__ float Ws[64][17];
    int tid = threadIdx.x, wv = tid >> 6, ln = tid & 63, g = ln >> 4, lo = ln & 15;

    for (int i = tid; i < 64 * 16; i += 256) {
        int r = i >> 4, c8 = i & 15;
        *(u16x8*)&Khi[r][c8 * 8] = *(const u16x8*)&ik_hi[(long)(k0 + r) * IDIM + c8 * 8];
        *(u16x8*)&Klo[r][c8 * 8] = *(const u16x8*)&ik_lo[(long)(k0 + r) * IDIM + c8 * 8];
    }
    for (int i = tid; i < 64 * 16; i += 256)
        Ws[i >> 4][i & 15] = w[(long)(q0 + (i >> 4)) * NH + (i & 15)];
    __syncthreads();

    float fin[4][4][4] = {};   // [mt][nt][r]
    #pragma unroll
    for (int hh = 0; hh < 4; hh++) {
        int h = wv * 4 + hh;
        #pragma unroll
        for (int mg = 0; mg < 2; mg++) {
            f32x4 acc[2][4] = {};
            #pragma unroll
            for (int kc = 0; kc < 4; kc++) {
                s16x8 ah[2], al[2];
                #pragma unroll
                for (int mi = 0; mi < 2; mi++) {
                    long off = ((long)(q0 + (mg * 2 + mi) * 16 + lo) * NH + h) * IDIM + kc * 32 + g * 8;
                    ah[mi] = *(const s16x8*)&iq_hi[off];
                    al[mi] = *(const s16x8*)&iq_lo[off];
                }
                #pragma unroll
                for (int nt = 0; nt < 4; nt++) {
                    s16x8 bh = *(const s16x8*)&Khi[nt * 16 + lo][kc * 32 + g * 8];
                    s16x8 bl = *(const s16x8*)&Klo[nt * 16 + lo][kc * 32 + g * 8];
                    #pragma unroll
                    for (int mi = 0; mi < 2; mi++) {
                        acc[mi][nt] = __builtin_amdgcn_mfma_f32_16x16x32_bf16(ah[mi], bh, acc[mi][nt], 0, 0, 0);
                        acc[mi][nt] = __builtin_amdgcn_mfma_f32_16x16x32_bf16(ah[mi], bl, acc[mi][nt], 0, 0, 0);
                        acc[mi][nt] = __builtin_amdgcn_mfma_f32_16x16x32_bf16(al[mi], bh, acc[mi][nt], 0, 0, 0);
                    }
                }
            }
            #pragma unroll
            for (int mi = 0; mi < 2; mi++) {
                int mt = mg * 2 + mi;
                #pragma unroll
                for (int r = 0; r < 4; r++) {
                    float wqh = Ws[mt * 16 + g * 4 + r][h];
                    #pragma unroll
                    for (int nt = 0; nt < 4; nt++) {
                        float v = acc[mi][nt][r] * SCALING;
                        v = v > 0.f ? v : 0.f;
                        fin[mt][nt][r] += v * wqh;
                    }
                }
            }
        }
    }
    __syncthreads();
    float (*FinBuf)[68] = (float(*)[68])&Khi[0][0];
    for (int wt = 0; wt < 4; wt++) {
        if (wv == wt) {
            #pragma unroll
            for (int mt = 0; mt < 4; mt++)
                #pragma unroll
                for (int r = 0; r < 4; r++)
                    #pragma unroll
                    for (int nt = 0; nt < 4; nt++) {
                        if (wt == 0) FinBuf[mt * 16 + g * 4 + r][nt * 16 + lo] = fin[mt][nt][r];
                        else         FinBuf[mt * 16 + g * 4 + r][nt * 16 + lo] += fin[mt][nt][r];
                    }
        }
        __syncthreads();
    }
    for (int i = tid; i < 64 * 16; i += 256) {
        int r = i >> 4, c4 = i & 15;
        *(f32x4*)&sc[(long)(q0 + r) * S_LEN + k0 + c4 * 4] = *(f32x4*)&FinBuf[r][c4 * 4];
    }
}

// ---------------------------------------------------------------------------
// Exact top-1024 per row via radix-select on float bits (scores >= 0).
// ---------------------------------------------------------------------------
__device__ __forceinline__ int block_scan_excl(int v, volatile int* lds, int tid, int* total)
{
    lds[tid] = v;
    __syncthreads();
    int x = v;
    for (int off = 1; off < 256; off <<= 1) {
        int y = (tid >= off) ? lds[tid - off] : 0;
        __syncthreads();
        x += y;
        lds[tid] = x;
        __syncthreads();
    }
    int t = lds[255];
    __syncthreads();
    *total = t;
    return x - v;
}

__global__ __launch_bounds__(256)
void topk_kernel(const float* __restrict__ sc, int* __restrict__ sel_idx)
{
    __shared__ int lds[256];
    __shared__ int wsum[4];
    int q = blockIdx.x, tid = threadIdx.x;
    int n = q + 1;
    int* row_sel = sel_idx + (long)q * TOPK_K;
    if (n <= TOPK_K) {
        for (int i = tid; i < n; i += 256) row_sel[i] = i;
        return;
    }
    const float* row = sc + (long)q * S_LEN;
    unsigned bits[8];
    int base = tid * 8;
    #pragma unroll
    for (int i = 0; i < 8; i++) {
        int k = base + i;
        bits[i] = (k < n) ? __float_as_uint(row[k]) : 0u;
    }
    unsigned prefix = 0;
    for (int bit = 30; bit >= 0; bit--) {
        unsigned cand = prefix | (1u << bit);
        int c = 0;
        #pragma unroll
        for (int i = 0; i < 8; i++) c += (bits[i] >= cand) ? 1 : 0;
        for (int off = 32; off; off >>= 1) c += __shfl_down(c, off, 64);
        if ((tid & 63) == 0) wsum[tid >> 6] = c;
        __syncthreads();
        int total = wsum[0] + wsum[1] + wsum[2] + wsum[3];
        __syncthreads();
        if (total >= TOPK_K) prefix = cand;
    }
    unsigned v = prefix;
    int lgt = 0, leq = 0;
    #pragma unroll
    for (int i = 0; i < 8; i++) {
        int k = base + i;
        if (k >= n) break;
        if (bits[i] > v) lgt++;
        else if (bits[i] == v) leq++;
    }
    int tot_gt, tot_eq;
    int gt_off = block_scan_excl(lgt, lds, tid, &tot_gt);
    int eq_off = block_scan_excl(leq, lds, tid, &tot_eq);
    int fill = TOPK_K - tot_gt;
    int gpos = gt_off, epos = eq_off;
    for (int i = 0; i < 8; i++) {
        int k = base + i;
        if (k >= n) break;
        if (bits[i] > v) {
            row_sel[gpos++] = k;
        } else if (bits[i] == v) {
            if (epos < fill) row_sel[tot_gt + epos] = k;
            epos++;
        }
    }
}

// ---------------------------------------------------------------------------
// bf16 packs for the attention path
// ---------------------------------------------------------------------------
__global__ void pack_kv(const float* __restrict__ k_pass, const float* __restrict__ k_rot,
                        __hip_bfloat16* __restrict__ kvb)
{
    int k = blockIdx.x;
    for (int i = threadIdx.x; i < CDIM; i += 256) {
        float v = (i < KV_LORA) ? k_pass[(long)k * KV_LORA + i]
                                : k_rot[(long)k * ROPE_D + (i - KV_LORA)];
        kvb[(long)k * CDIM + i] = __float2bfloat16(v);
    }
}

__global__ void pack_qrot(const float* __restrict__ q_rot, __hip_bfloat16* __restrict__ Qcat)
{
    int q = blockIdx.x;
    for (int j = threadIdx.x; j < NH * ROPE_D; j += 256) {
        int h = j >> 6, i = j & 63;
        Qcat[((long)q * NH + h) * CDIM + KV_LORA + i] =
            __float2bfloat16(q_rot[((long)h * S_LEN + q) * ROPE_D + i]);
    }
}

// ---------------------------------------------------------------------------
// MLA sparse attention v10: v7 base (verified, 304us) with PV restructured
// to route the V-transpose through the MATRIX pipe (7% busy) instead of the
// saturated DS pipe:
//   - transpose: read V[16key][32dim] as an A-frag b128 (same addressing
//     form as the verified S reads), MFMA against a constant SELECTOR
//     matrix Bsel_h[k][n] = delta(k, n+16h). Output D[key][dim-half] lands
//     in C-layout: lane (lo,g) = V[a*16+g*4+r][16h+lo] — the lane
//     transpose is done by the matrix pipe.
//   - PV: one K=32 MFMA per 16-dim chunk with a PERMUTED key ordering
//     kappa(g,j) = (j>>2)*16 + g*4 + (j&3) applied consistently to BOTH
//     operands: pa becomes a pure per-lane pack of pv[0..7] (the 8
//     ds_permute shuffles of the old pa build are deleted), and the B-frag
//     is cvt(bf16) of the two selector outputs (a=0 -> elems 0..3,
//     a=1 -> elems 4..7).
// Deletes 64 scalar ds_read_u16 + 8 shfl per wave/tile (the DS-pipe whale,
// ~590+90 of ~975 cycles); adds 8 b128 reads + 24 MFMA + ~100 VALU.
// Plain v7 LDS layout (v9 swizzle reverted - measured no-op).
// LDS = 73,728 + 4,096 = 77,824 -> 2 blocks/CU.
// ---------------------------------------------------------------------------
__global__ __launch_bounds__(256, 2)
void attn_mla10(const __hip_bfloat16* __restrict__ Qcat,
                const __hip_bfloat16* __restrict__ kvb,
                const int* __restrict__ sel_idx,
                unsigned short* __restrict__ Oout)   // == (unsigned short*)Qcat
{
    __shared__ __align__(16) unsigned int Kb[2][9216];   // 2 x 36,864 B
    __shared__ __align__(16) float Sp[4][64][4];         // 4,096 B partial-S

    const int q   = blockIdx.x;
    const int tid = threadIdx.x;
    const int wv  = tid >> 6;            // wave 0..3
    const int ln  = tid & 63;
    const int g   = ln >> 4, lo = ln & 15;
    const int kh  = wv >> 1, dh = wv & 1;   // S-split: key-half, dim-half
    const int k_l = ln >> 2, oct = ln & 3;  // staging roles
    const int cnt = (q + 1 < TOPK_K) ? (q + 1) : TOPK_K;
    const int* sel = sel_idx + (long)q * TOPK_K;
    const unsigned short* kvu = (const unsigned short*)kvb;
    const unsigned short* qrow = (const unsigned short*)Qcat + (long)q * NH * CDIM;

    // Q frags for this wave's 9 S-chunks (dims dh*288 + cc*32 + g*8)
    s16x8 Qf[9];
    #pragma unroll
    for (int cc = 0; cc < 9; cc++)
        Qf[cc] = *(const s16x8*)&qrow[lo * CDIM + (dh * 9 + cc) * 32 + g * 8];

    // Selector B-frags: Bsel_h[k][n] = delta(k, n+16h), lane (lo,g) holds
    // k = g*8+j, n = lo -> elem j = lo+16h-g*8 is 1.0 (when in range).
    s16x8 sel0v, sel1v;
    {
        unsigned onehot = (lo & 1) ? 0x3F800000u : 0x00003F80u;
        int w = (lo & 7) >> 1;
        i32x4 s0 = {0, 0, 0, 0}, s1 = {0, 0, 0, 0};
        #pragma unroll
        for (int ww = 0; ww < 4; ww++) {
            s0[ww] = (g == (lo >> 3)     && w == ww) ? (int)onehot : 0;
            s1[ww] = (g == 2 + (lo >> 3) && w == ww) ? (int)onehot : 0;
        }
        sel0v = __builtin_bit_cast(s16x8, s0);
        sel1v = __builtin_bit_cast(s16x8, s1);
    }
    const f32x4 fzero = {0.f, 0.f, 0.f, 0.f};

    float m_run = -1e30f, l_run = 0.f;
    f32x4 O[8];
    #pragma unroll
    for (int s = 0; s < 8; s++) O[s] = (f32x4){0.f, 0.f, 0.f, 0.f};

    const int ntl = (cnt + 31) >> 5;

    // staging: unit u = wv*9+uu, khu = u&1 (key-half), cu = u>>1 (32-dim chunk)
    // lane gathers key khu*16+k_l, dims cu*32 + oct*8 .. +8 (16B)
    // LDS byte = (cu*2+(oct>>1))*1024 + key*32 + (oct&1)*16

    // ---- prologue: stage tile 0 ----
    f32x4 Vst[9];
    int i0 = ln & 31;
    int selvA = sel[i0 < cnt ? i0 : cnt - 1];
    #pragma unroll
    for (int uu = 0; uu < 9; uu++) {
        int u = wv * 9 + uu, khu = u & 1, cu = u >> 1;
        int row = __shfl(selvA, khu * 16 + k_l, 64);
        Vst[uu] = *(const f32x4*)(kvu + (long)row * CDIM + cu * 32 + oct * 8);
    }
    #pragma unroll
    for (int uu = 0; uu < 9; uu++) {
        int u = wv * 9 + uu, khu = u & 1, cu = u >> 1;
        int byte = (cu * 2 + (oct >> 1)) * 1024 + (khu * 16 + k_l) * 32 + (oct & 1) * 16;
        *(f32x4*)((char*)&Kb[0][0] + byte) = Vst[uu];
    }
    int i1 = 32 + (ln & 31);
    int selvN = sel[i1 < cnt ? i1 : cnt - 1];
    __syncthreads();

    // S-read lane base: byte(key=kh*16+lo, D=c*32+g*8)
    //   = ((c*4+g)>>1)*1024 + (kh*16+lo)*32 + (g&1)*16
    const int sread_key = (kh * 16 + lo) * 32 + ((g & 1) << 4);
    int cur = 0;

    for (int t = 0; t < ntl; t++) {
        const int kb = t * 32;
        const bool hasn = (t + 1 < ntl);

        // --- issue next tile's gathers (fly over this tile's compute)
        if (hasn) {
            #pragma unroll
            for (int uu = 0; uu < 9; uu++) {
                int u = wv * 9 + uu, khu = u & 1, cu = u >> 1;
                int row = __shfl(selvN, khu * 16 + k_l, 64);
                Vst[uu] = *(const f32x4*)(kvu + (long)row * CDIM + cu * 32 + oct * 8);
            }
        }
        int ni = kb + 64 + (ln & 31);
        int selvNN = sel[ni < cnt ? ni : cnt - 1];

        // --- S partial: 9 chunks (this wave's dims), keys kh*16..+16
        const char* Kc = (const char*)&Kb[cur][0];
        f32x4 Sacc = (f32x4){0.f, 0.f, 0.f, 0.f};
        #pragma unroll
        for (int cc = 0; cc < 9; cc++) {
            int c = dh * 9 + cc;
            s16x8 av = *(const s16x8*)(Kc + ((c * 4 + g) >> 1) * 1024 + sread_key);
            Sacc = __builtin_amdgcn_mfma_f32_16x16x32_bf16(av, Qf[cc], Sacc, 0, 0, 0);
        }
        *(f32x4*)&Sp[wv][ln][0] = Sacc;
        __syncthreads();   // sync1: partials ready

        f32x4 S0 = *(const f32x4*)&Sp[0][ln][0];
        { f32x4 tmp = *(const f32x4*)&Sp[1][ln][0]; S0 += tmp; }
        f32x4 S1 = *(const f32x4*)&Sp[2][ln][0];
        { f32x4 tmp = *(const f32x4*)&Sp[3][ln][0]; S1 += tmp; }

        // --- online softmax over 32 keys (head = lo, replicated across quads)
        float pv[8];
        float mx = -1e30f;
        #pragma unroll
        for (int r = 0; r < 4; r++) {
            float s = S0[r] * SCALING;
            if (kb + g * 4 + r >= cnt) s = -1e30f;
            pv[r] = s;
            mx = fmaxf(mx, s);
        }
        #pragma unroll
        for (int r = 0; r < 4; r++) {
            float s = S1[r] * SCALING;
            if (kb + 16 + g * 4 + r >= cnt) s = -1e30f;
            pv[4 + r] = s;
            mx = fmaxf(mx, s);
        }
        mx = fmaxf(mx, __shfl_xor(mx, 16, 64));
        mx = fmaxf(mx, __shfl_xor(mx, 32, 64));
        float mn = fmaxf(m_run, mx);
        float al = __expf(m_run - mn);
        float sum = 0.f;
        #pragma unroll
        for (int j = 0; j < 8; j++) { float e = __expf(pv[j] - mn); pv[j] = e; sum += e; }
        sum += __shfl_xor(sum, 16, 64);
        sum += __shfl_xor(sum, 32, 64);
        m_run = mn;
        l_run = l_run * al + sum;

        // --- pa frag: permuted-k pack, PURE per-lane (no shuffles).
        // A[h=lo][k=g*8+j] = P[lo][kappa(g,j)], kappa = (j>>2)*16+g*4+(j&3)
        // = exactly pv[j].
        s16x8 pa;
        #pragma unroll
        for (int e = 0; e < 8; e++) pa[e] = (short)bf16_bits(pv[e]);

        // --- rescale O by per-head alpha (head = g*4+r)
        float alh[4];
        #pragma unroll
        for (int r = 0; r < 4; r++) alh[r] = __shfl(al, g * 4 + r, 64);
        #pragma unroll
        for (int s = 0; s < 8; s++) {
            O[s][0] *= alh[0]; O[s][1] *= alh[1]; O[s][2] *= alh[2]; O[s][3] *= alh[3];
        }

        // --- PV via matrix-pipe transpose: for each 32-dim group cc of this
        // wave's 128 dims, read V A-frags (keys a*16..+16 x dims c*32..+32),
        // selector-MFMA to C-layout, cvt to bf16 B-frags, PV MFMA (K=32).
        #pragma unroll
        for (int cc = 0; cc < 4; cc++) {
            int c = wv * 4 + cc;
            const char* abase = Kc + (c * 2 + (g >> 1)) * 1024 + ((g & 1) << 4);
            s16x8 vt0 = *(const s16x8*)(abase + lo * 32);          // keys 0..15
            s16x8 vt1 = *(const s16x8*)(abase + (16 + lo) * 32);   // keys 16..31
            f32x4 d00 = __builtin_amdgcn_mfma_f32_16x16x32_bf16(vt0, sel0v, fzero, 0, 0, 0);
            f32x4 d01 = __builtin_amdgcn_mfma_f32_16x16x32_bf16(vt0, sel1v, fzero, 0, 0, 0);
            f32x4 d10 = __builtin_amdgcn_mfma_f32_16x16x32_bf16(vt1, sel0v, fzero, 0, 0, 0);
            f32x4 d11 = __builtin_amdgcn_mfma_f32_16x16x32_bf16(vt1, sel1v, fzero, 0, 0, 0);
            // B-frag[k=g*8+j][n=lo] = V[kappa(g,j)][dim]:
            //   j=0..3 -> keys g*4+j   (a=0, d0h[r]),
            //   j=4..7 -> keys 16+g*4+(j-4) (a=1, d1h[r])
            s16x8 bv0, bv1;
            #pragma unroll
            for (int r = 0; r < 4; r++) {
                bv0[r]     = (short)bf16_bits(d00[r]);
                bv0[4 + r] = (short)bf16_bits(d10[r]);
                bv1[r]     = (short)bf16_bits(d01[r]);
                bv1[4 + r] = (short)bf16_bits(d11[r]);
            }
            O[cc * 2]     = __builtin_amdgcn_mfma_f32_16x16x32_bf16(pa, bv0, O[cc * 2], 0, 0, 0);
            O[cc * 2 + 1] = __builtin_amdgcn_mfma_f32_16x16x32_bf16(pa, bv1, O[cc * 2 + 1], 0, 0, 0);
        }

        // --- commit next tile (compiler inserts vmcnt wait for Vst here)
        if (hasn) {
            char* Kn = (char*)&Kb[cur ^ 1][0];
            #pragma unroll
            for (int uu = 0; uu < 9; uu++) {
                int u = wv * 9 + uu, khu = u & 1, cu = u >> 1;
                int byte = (cu * 2 + (oct >> 1)) * 1024 + (khu * 16 + k_l) * 32 + (oct & 1) * 16;
                *(f32x4*)(Kn + byte) = Vst[uu];
            }
        }
        __syncthreads();   // sync2: staging done, Kb[cur]/Sp fully consumed
        cur ^= 1;
        selvN = selvNN;
    }

    // --- epilogue: O / l -> bf16, wave's own 128-dim slice of the Qcat row
    float linv[4];
    #pragma unroll
    for (int r = 0; r < 4; r++) linv[r] = 1.f / __shfl(l_run, g * 4 + r, 64);
    unsigned short* orow = Oout + (long)q * NH * CDIM;
    #pragma unroll
    for (int s = 0; s < 8; s++)
        #pragma unroll
        for (int r = 0; r < 4; r++)
            orow[(g * 4 + r) * KV_LORA + wv * 128 + s * 16 + lo] = bf16_bits(O[s][r] * linv[r]);
}

// ---------------------------------------------------------------------------
// Launch
// ---------------------------------------------------------------------------
extern "C" void kernel_launch(void* const* d_in, const int* in_sizes, int n_in,
                              void* d_out, int out_size, void* d_ws, size_t ws_size,
                              hipStream_t stream)
{
    const float* q_latent = (const float*)d_in[0];   // (2048,1536)
    const float* hidden   = (const float*)d_in[1];   // (2048,2048)
    const float* cosp     = (const float*)d_in[2];   // (2048,64)
    const float* sinp     = (const float*)d_in[3];   // (2048,64)
    const float* q_pass   = (const float*)d_in[4];   // (16,2048,128)
    const float* q_rot    = (const float*)d_in[5];   // (16,2048,64)
    const float* k_pass   = (const float*)d_in[6];   // (2048,512)
    const float* k_rot    = (const float*)d_in[7];   // (2048,64)
    const float* kv_b     = (const float*)d_in[9];   // (4096,512)
    const float* wq_b_w   = (const float*)d_in[10];  // (2048,1536)
    const float* wk_w     = (const float*)d_in[11];  // (128,2048)
    const float* k_norm_w = (const float*)d_in[12];  // (64)
    const float* wproj_w  = (const float*)d_in[13];  // (16,2048)
    const float* wproj_b  = (const float*)d_in[14];  // (16)

    float* ws = (float*)d_ws;
    // Persistent: sel_idx
    int* sel_idx = (int*)ws;                                       // [0 .. 2,097,152)
    // Phase 1a: split inputs for ql GEMM
    unsigned short* qlat_hi = (unsigned short*)(ws + 2097152);
    unsigned short* qlat_lo = (unsigned short*)(ws + 3670016);
    unsigned short* wq_hi   = (unsigned short*)(ws + 5242880);
    unsigned short* wq_lo   = (unsigned short*)(ws + 6815744);     // ends 8,388,608 f
    float* ql = ws + 8388608;                                      // 4,194,304 f -> 12,582,912
    // Phase 1b (after ql GEMM; aliases qlat/wq region):
    unsigned short* iq_hi = (unsigned short*)(ws + 2097152);
    unsigned short* iq_lo = (unsigned short*)(ws + 4194304);
    unsigned short* ik_hi = (unsigned short*)(ws + 6291456);
    unsigned short* ik_lo = (unsigned short*)(ws + 6422528);
    float* wmat = ws + 6553600;                                    // 32,768 f
    float* ckv  = ws + 6586368;                                    // 262,144 f -> 6,848,512
    float* sc   = ws + 8388608;                                    // aliases ql (dead after pack iq)
    float* part = ws + 12582912;                                   // 2,359,296 f -> 14,942,208 (phase 1 only)
    // Phase 2 (after topk; aliases phase-1):
    __hip_bfloat16* Qcat = (__hip_bfloat16*)(ws + 2097152);        // ends f-off 11,534,336; O written in-place
    __hip_bfloat16* kvb  = (__hip_bfloat16*)(ws + 11534336);       // -> 12,124,160
    unsigned short* kbT  = (unsigned short*)(ws + 12124160);       // -> 12,648,448
    unsigned short* vb   = (unsigned short*)(ws + 12648448);       // -> 13,172,736
    unsigned short* qp   = (unsigned short*)(ws + 13172736);       // -> 15,269,888  (61.1 MB peak)

    dim3 b256(256);
    // --- indexer path (split-bf16 MFMA, selection-exact) ---
    pack_split<<<dim3(12288), b256, 0, stream>>>(q_latent, qlat_hi, qlat_lo, 2048L * 1536);
    pack_split<<<dim3(12288), b256, 0, stream>>>(wq_b_w, wq_hi, wq_lo, 2048L * 1536);
    gemm_split3<<<dim3(32, 32), b256, 0, stream>>>(qlat_hi, qlat_lo, wq_hi, wq_lo,
        ql, 2048, 1536, 1536, 1536, 2048);
    rope_iq_inplace<<<dim3(2048, 16), dim3(64), 0, stream>>>(ql, cosp, sinp);
    pack_split<<<dim3(16384), b256, 0, stream>>>(ql, iq_hi, iq_lo, 2048L * 2048);
    proj_splitk<<<dim3(3, 32, 8), b256, 0, stream>>>(hidden, wk_w, wproj_w, part);
    proj_reduce<<<dim3((S_LEN * 144 + 255) / 256), b256, 0, stream>>>(part, ckv, wmat);
    build_ik_inplace<<<dim3(2048), dim3(64), 0, stream>>>(ckv, cosp, sinp, k_norm_w);
    pack_split<<<dim3(1024), b256, 0, stream>>>(ckv, ik_hi, ik_lo, 2048L * 128);
    absbias_inplace<<<dim3(128), b256, 0, stream>>>(wmat, wproj_b);
    scores_mfma<<<dim3(32, 32), b256, 0, stream>>>(iq_hi, iq_lo, ik_hi, ik_lo, wmat, sc);
    topk_kernel<<<dim3(2048), b256, 0, stream>>>(sc, sel_idx);

    // --- attention path (bf16 MFMA, compressed space) ---
    pack_bf16<<<dim3(16384), b256, 0, stream>>>(q_pass, qp, 16L * 2048 * 128);
    pack_kbT<<<dim3(4096), b256, 0, stream>>>(kv_b, kbT);
    pack_vb<<<dim3(4096), b256, 0, stream>>>(kv_b, vb);
    pack_kv<<<dim3(2048), b256, 0, stream>>>(k_pass, k_rot, kvb);
    // q_abs[h] = qp[h] (2048x128) @ kbT[h]^T (512x128): K=128 -> Qcat[:, h, 0:512]
    gemm_bf16<__hip_bfloat16><<<dim3(8, 32, 16), b256, 0, stream>>>(
        qp, kbT, (__hip_bfloat16*)Qcat, 128, 128, 128, NH * CDIM,
        2048L * 128, 512L * 128, (long)CDIM);
    pack_qrot<<<dim3(2048), b256, 0, stream>>>(q_rot, Qcat);

    // Work-split pipelined attention, matrix-pipe V-transpose PV.
    attn_mla10<<<dim3(2048), dim3(256), 0, stream>>>(Qcat, kvb, sel_idx,
                                                     (unsigned short*)Qcat);
    // out[q][h][d] = O[q][h][:512] . vb[h][d][:512]; O rows live inside Qcat
    // (row stride NH*CDIM=9216, head offset h*512).
    gemm_bf16<float><<<dim3(2, 32, 16), b256, 0, stream>>>(
        (const unsigned short*)Qcat, vb, (float*)d_out,
        512, NH * CDIM, KV_LORA, NH * IDIM,
        512L, 128L * 512, (long)IDIM);
}